// Round 5
// baseline (1219.314 us; speedup 1.0000x reference)
//
#include <hip/hip_runtime.h>
#include <hip/hip_fp16.h>
#include <hip/hip_cooperative_groups.h>

namespace cg = cooperative_groups;

// Problem constants
constexpr int NN   = 50000;
constexpr int EE   = 800000;
constexpr int INF  = 128;   // input feat
constexpr int NH   = 4;     // heads
constexpr int GEMM_ROWS = (NN + 63) / 64;   // 782
constexpr int NCH  = (NN + 255) / 256;      // 196 scan chunks

struct __align__(8) h4 { __half2 a, b; };   // 4 halves = 8 bytes

__device__ __forceinline__ float elw(float a) {
    a = (a > 0.f) ? a : 0.2f * a;          // leaky_relu(0.2)
    return __expf(a);                       // exp without max-sub (scores bounded)
}

// ================= device helpers (bodies identical to proven R4 kernels) =================

template <int CH, bool HOUT>
__device__ __forceinline__ void gemm_att_tile(const float* __restrict__ A,
                                              const float* __restrict__ B,
                                              void* __restrict__ Cv,
                                              const float* __restrict__ att_s,
                                              const float* __restrict__ att_d,
                                              float* __restrict__ a_s,
                                              float* __restrict__ a_d,
                                              int N, int K, int M,
                                              int row0, int col0, int tid,
                                              float (*As)[68], float (*Bs)[64]) {
    const int tx = tid & 15, ty = tid >> 4;
    const int col  = col0 + tx * 4;
    const int head = col / CH;
    const int pos  = col % CH;
    float attS[4], attD[4];
    #pragma unroll
    for (int j = 0; j < 4; ++j) {
        attS[j] = att_s[head * CH + pos + j];
        attD[j] = att_d[head * CH + pos + j];
    }
    float acc[4][4] = {};
    for (int k0 = 0; k0 < K; k0 += 16) {
        {
            const int a_row = tid >> 2;
            const int a_k   = (tid & 3) * 4;
            const int gr    = row0 + a_row;
            float4 v = make_float4(0.f, 0.f, 0.f, 0.f);
            if (gr < N) v = *(const float4*)(A + (size_t)gr * K + k0 + a_k);
            As[a_k + 0][a_row] = v.x;
            As[a_k + 1][a_row] = v.y;
            As[a_k + 2][a_row] = v.z;
            As[a_k + 3][a_row] = v.w;
        }
        {
            const int b_k = tid >> 4;
            const int b_c = (tid & 15) * 4;
            float4 w = *(const float4*)(B + (size_t)(k0 + b_k) * M + col0 + b_c);
            *(float4*)&Bs[b_k][b_c] = w;
        }
        __syncthreads();
        #pragma unroll
        for (int kk = 0; kk < 16; ++kk) {
            float4 a = *(const float4*)&As[kk][ty * 4];
            float4 b = *(const float4*)&Bs[kk][tx * 4];
            const float av[4] = {a.x, a.y, a.z, a.w};
            const float bv[4] = {b.x, b.y, b.z, b.w};
            #pragma unroll
            for (int i = 0; i < 4; ++i)
                #pragma unroll
                for (int j = 0; j < 4; ++j)
                    acc[i][j] = fmaf(av[i], bv[j], acc[i][j]);
        }
        __syncthreads();
    }
    #pragma unroll
    for (int i = 0; i < 4; ++i) {
        const int r = row0 + ty * 4 + i;
        if (r < N) {
            if constexpr (HOUT) {
                __half* C  = (__half*)Cv;
                __half* cp = C + (size_t)r * M + col0 + tx * 4;
                __half2 q0 = __halves2half2(__float2half_rn(acc[i][0]), __float2half_rn(acc[i][1]));
                __half2 q1 = __halves2half2(__float2half_rn(acc[i][2]), __float2half_rn(acc[i][3]));
                *(__half2*)cp       = q0;
                *(__half2*)(cp + 2) = q1;
            } else {
                float* C  = (float*)Cv;
                float* cp = C + (size_t)r * M + col0 + tx * 4;
                cp[0] = acc[i][0]; cp[1] = acc[i][1]; cp[2] = acc[i][2]; cp[3] = acc[i][3];
            }
        }
        float ss = 0.f, sd = 0.f;
        #pragma unroll
        for (int j = 0; j < 4; ++j) {
            ss = fmaf(acc[i][j], attS[j], ss);
            sd = fmaf(acc[i][j], attD[j], sd);
        }
        #pragma unroll
        for (int msk = 1; msk < CH / 4; msk <<= 1) {
            ss += __shfl_xor(ss, msk, 64);
            sd += __shfl_xor(sd, msk, 64);
        }
        if ((tx & (CH / 4 - 1)) == 0 && r < N) {
            a_s[r * NH + head] = ss;
            a_d[r * NH + head] = sd;
        }
    }
}

__device__ __forceinline__ void gemm_pq_tile(const float* __restrict__ A,
                                             const float* __restrict__ B,
                                             __half* __restrict__ C,
                                             int N, int K, int M,
                                             int row0, int col0, int tid,
                                             float (*As)[68], float (*Bs)[64]) {
    const int tx = tid & 15, ty = tid >> 4;
    float acc[4][4] = {};
    for (int k0 = 0; k0 < K; k0 += 16) {
        {
            const int a_row = tid >> 2;
            const int a_k   = (tid & 3) * 4;
            const int gr    = row0 + a_row;
            float4 v = make_float4(0.f, 0.f, 0.f, 0.f);
            if (gr < N) v = *(const float4*)(A + (size_t)gr * K + k0 + a_k);
            As[a_k + 0][a_row] = v.x;
            As[a_k + 1][a_row] = v.y;
            As[a_k + 2][a_row] = v.z;
            As[a_k + 3][a_row] = v.w;
        }
        {
            const int b_k = tid >> 4;
            const int b_c = (tid & 15) * 4;
            float4 w = *(const float4*)(B + (size_t)(k0 + b_k) * M + col0 + b_c);
            *(float4*)&Bs[b_k][b_c] = w;
        }
        __syncthreads();
        #pragma unroll
        for (int kk = 0; kk < 16; ++kk) {
            float4 a = *(const float4*)&As[kk][ty * 4];
            float4 b = *(const float4*)&Bs[kk][tx * 4];
            const float av[4] = {a.x, a.y, a.z, a.w};
            const float bv[4] = {b.x, b.y, b.z, b.w};
            #pragma unroll
            for (int i = 0; i < 4; ++i)
                #pragma unroll
                for (int j = 0; j < 4; ++j)
                    acc[i][j] = fmaf(av[i], bv[j], acc[i][j]);
        }
        __syncthreads();
    }
    #pragma unroll
    for (int i = 0; i < 4; ++i) {
        const int r = row0 + ty * 4 + i;
        if (r < N) {
            __half* cp = C + (size_t)r * M + col0 + tx * 4;
            __half2 q0 = __halves2half2(__float2half_rn(acc[i][0]), __float2half_rn(acc[i][1]));
            __half2 q1 = __halves2half2(__float2half_rn(acc[i][2]), __float2half_rn(acc[i][3]));
            *(__half2*)cp       = q0;
            *(__half2*)(cp + 2) = q1;
        }
    }
}

__device__ __forceinline__ void softagg1_node(int n, int lane,
                                              const int* __restrict__ rowptr,
                                              const int* __restrict__ psrc,
                                              const float* __restrict__ a_s,
                                              const float* __restrict__ a_d,
                                              const __half* __restrict__ xl,
                                              const float* __restrict__ bias,
                                              float* __restrict__ out) {
    const int r0 = rowptr[n], r1 = rowptr[n + 1];
    const int hh = lane >> 4;
    const float ad = a_d[n * NH + hh];

    const h4* X = (const h4*)xl;   // row stride 64 h4 units (256 halves)
    float4 A0 = {0,0,0,0}, A1 = {0,0,0,0}, A2 = {0,0,0,0}, A3 = {0,0,0,0};
    float sum = 0.f;
    int j = r0;
    for (; j + 7 < r1; j += 8) {
        const int s0 = psrc[j],     s1 = psrc[j + 1], s2 = psrc[j + 2], s3 = psrc[j + 3];
        const int s4 = psrc[j + 4], s5 = psrc[j + 5], s6 = psrc[j + 6], s7 = psrc[j + 7];
        const float w0 = elw(a_s[s0 * NH + hh] + ad);
        const float w1 = elw(a_s[s1 * NH + hh] + ad);
        const float w2 = elw(a_s[s2 * NH + hh] + ad);
        const float w3 = elw(a_s[s3 * NH + hh] + ad);
        const float w4 = elw(a_s[s4 * NH + hh] + ad);
        const float w5 = elw(a_s[s5 * NH + hh] + ad);
        const float w6 = elw(a_s[s6 * NH + hh] + ad);
        const float w7 = elw(a_s[s7 * NH + hh] + ad);
        sum += ((w0 + w1) + (w2 + w3)) + ((w4 + w5) + (w6 + w7));
        const h4 v0 = X[(size_t)s0 * 64 + lane];
        const h4 v1 = X[(size_t)s1 * 64 + lane];
        const h4 v2 = X[(size_t)s2 * 64 + lane];
        const h4 v3 = X[(size_t)s3 * 64 + lane];
        const h4 v4 = X[(size_t)s4 * 64 + lane];
        const h4 v5 = X[(size_t)s5 * 64 + lane];
        const h4 v6 = X[(size_t)s6 * 64 + lane];
        const h4 v7 = X[(size_t)s7 * 64 + lane];
        float2 l0 = __half22float2(v0.a), m0 = __half22float2(v0.b);
        float2 l1 = __half22float2(v1.a), m1 = __half22float2(v1.b);
        float2 l2 = __half22float2(v2.a), m2 = __half22float2(v2.b);
        float2 l3 = __half22float2(v3.a), m3 = __half22float2(v3.b);
        float2 l4 = __half22float2(v4.a), m4 = __half22float2(v4.b);
        float2 l5 = __half22float2(v5.a), m5 = __half22float2(v5.b);
        float2 l6 = __half22float2(v6.a), m6 = __half22float2(v6.b);
        float2 l7 = __half22float2(v7.a), m7 = __half22float2(v7.b);
        A0.x = fmaf(w0, l0.x, A0.x); A0.y = fmaf(w0, l0.y, A0.y);
        A0.z = fmaf(w0, m0.x, A0.z); A0.w = fmaf(w0, m0.y, A0.w);
        A1.x = fmaf(w1, l1.x, A1.x); A1.y = fmaf(w1, l1.y, A1.y);
        A1.z = fmaf(w1, m1.x, A1.z); A1.w = fmaf(w1, m1.y, A1.w);
        A2.x = fmaf(w2, l2.x, A2.x); A2.y = fmaf(w2, l2.y, A2.y);
        A2.z = fmaf(w2, m2.x, A2.z); A2.w = fmaf(w2, m2.y, A2.w);
        A3.x = fmaf(w3, l3.x, A3.x); A3.y = fmaf(w3, l3.y, A3.y);
        A3.z = fmaf(w3, m3.x, A3.z); A3.w = fmaf(w3, m3.y, A3.w);
        A0.x = fmaf(w4, l4.x, A0.x); A0.y = fmaf(w4, l4.y, A0.y);
        A0.z = fmaf(w4, m4.x, A0.z); A0.w = fmaf(w4, m4.y, A0.w);
        A1.x = fmaf(w5, l5.x, A1.x); A1.y = fmaf(w5, l5.y, A1.y);
        A1.z = fmaf(w5, m5.x, A1.z); A1.w = fmaf(w5, m5.y, A1.w);
        A2.x = fmaf(w6, l6.x, A2.x); A2.y = fmaf(w6, l6.y, A2.y);
        A2.z = fmaf(w6, m6.x, A2.z); A2.w = fmaf(w6, m6.y, A2.w);
        A3.x = fmaf(w7, l7.x, A3.x); A3.y = fmaf(w7, l7.y, A3.y);
        A3.z = fmaf(w7, m7.x, A3.z); A3.w = fmaf(w7, m7.y, A3.w);
    }
    for (; j < r1; ++j) {
        const int s0 = psrc[j];
        const float w0 = elw(a_s[s0 * NH + hh] + ad);
        sum += w0;
        const h4 v0 = X[(size_t)s0 * 64 + lane];
        float2 l0 = __half22float2(v0.a), m0 = __half22float2(v0.b);
        A0.x = fmaf(w0, l0.x, A0.x); A0.y = fmaf(w0, l0.y, A0.y);
        A0.z = fmaf(w0, m0.x, A0.z); A0.w = fmaf(w0, m0.y, A0.w);
    }
    const float inv = 1.f / (sum + 1e-30f);
    float4 t;
    t.x = ((A0.x + A1.x) + (A2.x + A3.x)) * inv;
    t.y = ((A0.y + A1.y) + (A2.y + A3.y)) * inv;
    t.z = ((A0.z + A1.z) + (A2.z + A3.z)) * inv;
    t.w = ((A0.w + A1.w) + (A2.w + A3.w)) * inv;
    #pragma unroll
    for (int msk = 16; msk < 64; msk <<= 1) {
        t.x += __shfl_xor(t.x, msk, 64);
        t.y += __shfl_xor(t.y, msk, 64);
        t.z += __shfl_xor(t.z, msk, 64);
        t.w += __shfl_xor(t.w, msk, 64);
    }
    if (lane < 16) {
        const float4 b = ((const float4*)bias)[lane];
        float4 o;
        o.x = t.x * 0.25f + b.x; o.y = t.y * 0.25f + b.y;
        o.z = t.z * 0.25f + b.z; o.w = t.w * 0.25f + b.w;
        ((float4*)out)[(size_t)n * 16 + lane] = o;
    }
}

__device__ __forceinline__ void softagg2_node(int n, int lane,
                                              const int* __restrict__ rowptr,
                                              const int* __restrict__ psrc,
                                              const float* __restrict__ a_s,
                                              const float* __restrict__ a_d,
                                              float* __restrict__ alpha_p,
                                              float* __restrict__ inv_s,
                                              const __half* __restrict__ xl,
                                              const float* __restrict__ bias,
                                              float* __restrict__ out) {
    const int r0 = rowptr[n], r1 = rowptr[n + 1];
    const int cl = lane & 31, half = lane >> 5, hh = cl >> 3;
    const float ad = a_d[n * NH + hh];
    const bool writer = (cl & 7) == 0;   // one lane per (half, head) writes raw w

    const h4* X = (const h4*)xl;   // row stride 32 h4 units (128 halves)
    float4 A0 = {0,0,0,0}, A1 = {0,0,0,0};
    float sum = 0.f;
    int j = r0;
    for (; j + 7 < r1; j += 8) {
        const int ja = j + half, jc = j + 2 + half, je = j + 4 + half, jg = j + 6 + half;
        const int sa = psrc[ja], sc = psrc[jc], se = psrc[je], sg = psrc[jg];
        const float wa = elw(a_s[sa * NH + hh] + ad);
        const float wc = elw(a_s[sc * NH + hh] + ad);
        const float we = elw(a_s[se * NH + hh] + ad);
        const float wg = elw(a_s[sg * NH + hh] + ad);
        if (writer) {
            alpha_p[ja * NH + hh] = wa; alpha_p[jc * NH + hh] = wc;
            alpha_p[je * NH + hh] = we; alpha_p[jg * NH + hh] = wg;
        }
        sum += (wa + wc) + (we + wg);
        const h4 va = X[(size_t)sa * 32 + cl];
        const h4 vc = X[(size_t)sc * 32 + cl];
        const h4 ve = X[(size_t)se * 32 + cl];
        const h4 vg = X[(size_t)sg * 32 + cl];
        const float2 la = __half22float2(va.a), ma = __half22float2(va.b);
        const float2 lc = __half22float2(vc.a), mc = __half22float2(vc.b);
        const float2 le = __half22float2(ve.a), me = __half22float2(ve.b);
        const float2 lg = __half22float2(vg.a), mg = __half22float2(vg.b);
        A0.x = fmaf(wa, la.x, A0.x); A0.y = fmaf(wa, la.y, A0.y);
        A0.z = fmaf(wa, ma.x, A0.z); A0.w = fmaf(wa, ma.y, A0.w);
        A1.x = fmaf(wc, lc.x, A1.x); A1.y = fmaf(wc, lc.y, A1.y);
        A1.z = fmaf(wc, mc.x, A1.z); A1.w = fmaf(wc, mc.y, A1.w);
        A0.x = fmaf(we, le.x, A0.x); A0.y = fmaf(we, le.y, A0.y);
        A0.z = fmaf(we, me.x, A0.z); A0.w = fmaf(we, me.y, A0.w);
        A1.x = fmaf(wg, lg.x, A1.x); A1.y = fmaf(wg, lg.y, A1.y);
        A1.z = fmaf(wg, mg.x, A1.z); A1.w = fmaf(wg, mg.y, A1.w);
    }
    for (; j < r1; j += 2) {
        const int ja = j + half;
        const bool valid = ja < r1;
        const int sa = psrc[valid ? ja : r0];
        float wa = 0.f;
        if (valid) {
            wa = elw(a_s[sa * NH + hh] + ad);
            if (writer) alpha_p[ja * NH + hh] = wa;
        }
        sum += wa;
        const h4 va = X[(size_t)sa * 32 + cl];
        const float2 la = __half22float2(va.a), ma = __half22float2(va.b);
        A0.x = fmaf(wa, la.x, A0.x); A0.y = fmaf(wa, la.y, A0.y);
        A0.z = fmaf(wa, ma.x, A0.z); A0.w = fmaf(wa, ma.y, A0.w);
    }
    // merge halves' partial sums, then normalize
    sum += __shfl_xor(sum, 32, 64);
    const float inv = 1.f / (sum + 1e-30f);
    if (writer && half == 0) inv_s[n * NH + hh] = inv;

    float4 t;
    t.x = A0.x + A1.x; t.y = A0.y + A1.y; t.z = A0.z + A1.z; t.w = A0.w + A1.w;
    t.x += __shfl_xor(t.x, 32, 64);
    t.y += __shfl_xor(t.y, 32, 64);
    t.z += __shfl_xor(t.z, 32, 64);
    t.w += __shfl_xor(t.w, 32, 64);
    t.x *= inv; t.y *= inv; t.z *= inv; t.w *= inv;
    #pragma unroll
    for (int q = 0; q < 2; ++q) {
        const int msk = (q == 0) ? 8 : 16;
        t.x += __shfl_xor(t.x, msk, 64);
        t.y += __shfl_xor(t.y, msk, 64);
        t.z += __shfl_xor(t.z, msk, 64);
        t.w += __shfl_xor(t.w, msk, 64);
    }
    if (lane < 8) {
        const float4 b = ((const float4*)bias)[lane];
        float4 o;
        o.x = t.x * 0.25f + b.x; o.y = t.y * 0.25f + b.y;
        o.z = t.z * 0.25f + b.z; o.w = t.w * 0.25f + b.w;
        ((float4*)out)[(size_t)n * 8 + lane] = o;
    }
}

// ================= ONE persistent cooperative kernel: all 10 phases =================
// __launch_bounds__(256, 4): VGPR<=128 -> guaranteed 4 blocks/CU co-residency (matches
// softagg's previously-measured ~16 waves/CU occupancy, so gather latency hiding is kept).
__global__ __launch_bounds__(256, 4) void fused_gat(
    const float* x, const int* ei,
    const float* W1, const float* att1s, const float* att1d, const float* b1,
    const float* W3, const float* att3s, const float* att3d, const float* b3,
    const float* mW1, const float* mb1, const float* mW2, const float* mb2,
    float* out_nodes, float* out_edges,
    __half* xlh, float* h1, __half* xl2h, __half* PQh,
    float* alpha_p, float* a_s, float* a_d, float* W1pq, float* inv_s,
    int* deg, int* cursor, int* rowptr, int* perm, int* psrc, int* pdst,
    int* bsum, int* boff) {
    cg::grid_group grid = cg::this_grid();
    const int tid = threadIdx.x;
    const int bid = blockIdx.x;
    const int nB  = gridDim.x;
    const int gtid = bid * 256 + tid;
    const int gstride = nB * 256;
    const int lane = tid & 63, wv = tid >> 6;

    __shared__ float As[16][68];
    __shared__ float Bs[16][64];
    __shared__ int   sw[8];

    // ---- P0: zero deg; pack W1pq ----
    for (int i = gtid; i < NN; i += gstride) deg[i] = 0;
    for (int i = gtid; i < 32 * 128; i += gstride) {
        const int k = i >> 7, jj = i & 127;
        W1pq[i] = (jj < 64) ? mW1[k * 64 + jj] : mW1[(36 + k) * 64 + (jj - 64)];
    }
    grid.sync();

    // ---- P1: count degrees ----
    for (int e = gtid; e < EE; e += gstride) atomicAdd(&deg[ei[EE + e]], 1);
    grid.sync();

    // ---- P2a: per-chunk (256 elems) sums ----
    for (int c = bid; c < NCH; c += nB) {
        const int i = c * 256 + tid;
        int s = (i < NN) ? deg[i] : 0;
        #pragma unroll
        for (int d = 1; d < 64; d <<= 1) s += __shfl_xor(s, d, 64);
        if (lane == 0) sw[wv] = s;
        __syncthreads();
        if (tid == 0) bsum[c] = sw[0] + sw[1] + sw[2] + sw[3];
        __syncthreads();
    }
    grid.sync();

    // ---- P2b: block 0 exclusive-scans the NCH chunk sums ----
    if (bid == 0) {
        int v = (tid < NCH) ? bsum[tid] : 0;
        int incl = v;
        #pragma unroll
        for (int d = 1; d < 64; d <<= 1) {
            int t = __shfl_up(incl, d, 64);
            if (lane >= d) incl += t;
        }
        if (lane == 63) sw[wv] = incl;
        __syncthreads();
        if (wv == 0 && lane < 4) {
            int s4 = sw[lane];
            #pragma unroll
            for (int d = 1; d < 4; d <<= 1) {
                int t = __shfl_up(s4, d, 64);
                if (lane >= d) s4 += t;
            }
            sw[lane + 4] = s4;
        }
        __syncthreads();
        const int woff = (wv > 0) ? sw[wv - 1 + 4] : 0;
        if (tid < NCH) boff[tid] = woff + incl - v;
    }
    grid.sync();

    // ---- P2c: local exclusive scan + chunk offset -> rowptr, cursor ----
    for (int c = bid; c < NCH; c += nB) {
        const int i = c * 256 + tid;
        int v = (i < NN) ? deg[i] : 0;
        int incl = v;
        #pragma unroll
        for (int d = 1; d < 64; d <<= 1) {
            int t = __shfl_up(incl, d, 64);
            if (lane >= d) incl += t;
        }
        if (lane == 63) sw[wv] = incl;
        __syncthreads();
        if (wv == 0 && lane < 4) {
            int s4 = sw[lane];
            #pragma unroll
            for (int d = 1; d < 4; d <<= 1) {
                int t = __shfl_up(s4, d, 64);
                if (lane >= d) s4 += t;
            }
            sw[lane + 4] = s4;
        }
        __syncthreads();
        const int excl = boff[c] + ((wv > 0) ? sw[wv - 1 + 4] : 0) + incl - v;
        if (i < NN) { rowptr[i] = excl; cursor[i] = excl; }
        __syncthreads();
    }
    if (gtid == 0) rowptr[NN] = EE;
    grid.sync();

    // ---- P3+P4: scatter (needs cursor) and layer-1 GEMM (independent) ----
    for (int e = gtid; e < EE; e += gstride) {
        const int dd = ei[EE + e];
        const int p = atomicAdd(&cursor[dd], 1);
        perm[p] = e;
        psrc[p] = ei[e];
        pdst[p] = dd;
    }
    for (int t = bid; t < GEMM_ROWS * 4; t += nB)
        gemm_att_tile<64, true>(x, W1, xlh, att1s, att1d, a_s, a_d,
                                NN, INF, NH * 64,
                                (t % GEMM_ROWS) * 64, (t / GEMM_ROWS) * 64, tid, As, Bs);
    grid.sync();

    // ---- P5: layer-1 softmax+aggregate ----
    for (int n = bid * 4 + wv; n < NN; n += nB * 4)
        softagg1_node(n, lane, rowptr, psrc, a_s, a_d, xlh, b1, h1);
    grid.sync();

    // ---- P6: layer-2 GEMM ----
    for (int t = bid; t < GEMM_ROWS * 2; t += nB)
        gemm_att_tile<32, true>(h1, W3, xl2h, att3s, att3d, a_s, a_d,
                                NN, 64, NH * 32,
                                (t % GEMM_ROWS) * 64, (t / GEMM_ROWS) * 64, tid, As, Bs);
    grid.sync();

    // ---- P7: layer-2 softmax+aggregate ----
    for (int n = bid * 4 + wv; n < NN; n += nB * 4)
        softagg2_node(n, lane, rowptr, psrc, a_s, a_d, alpha_p, inv_s, xl2h, b3, out_nodes);
    grid.sync();

    // ---- P8: PQ GEMM (xl2h region dead -> PQh aliases it, safe after sync) ----
    for (int t = bid; t < GEMM_ROWS * 2; t += nB)
        gemm_pq_tile(out_nodes, W1pq, PQh, NN, 32, 128,
                     (t % GEMM_ROWS) * 64, (t / GEMM_ROWS) * 64, tid, As, Bs);
    grid.sync();

    // ---- P9: edge MLP ----
    {
        const int g = lane >> 4, c = lane & 15;
        const float4 wa0 = *(const float4*)&mW1[32 * 64 + c * 4];
        const float4 wa1 = *(const float4*)&mW1[33 * 64 + c * 4];
        const float4 wa2 = *(const float4*)&mW1[34 * 64 + c * 4];
        const float4 wa3 = *(const float4*)&mW1[35 * 64 + c * 4];
        const float4 b1v = *(const float4*)&mb1[c * 4];
        const float4 w2a = *(const float4*)&mW2[c * 8];
        const float4 w2b = *(const float4*)&mW2[c * 8 + 4];
        const float bo0 = mb2[0], bo1 = mb2[1];

        const h4* PQ4 = (const h4*)PQh;   // row stride 32 h4 units (128 halves)
        const int gw = bid * 4 + wv;
        const int stride4 = nB * 4 * 4;

        for (int jb = gw * 4; jb < EE; jb += stride4) {
            const int j = jb + g;
            const int s = psrc[j];
            const int d = pdst[j];
            const float4 ar = *(const float4*)&alpha_p[(size_t)j * 4];
            const float4 iv = *(const float4*)&inv_s[(size_t)d * 4];
            const float al0 = ar.x * iv.x, al1 = ar.y * iv.y;
            const float al2 = ar.z * iv.z, al3 = ar.w * iv.w;
            const h4 ph = PQ4[(size_t)s * 32 + c];
            const h4 qh = PQ4[(size_t)d * 32 + 16 + c];
            const float2 pl = __half22float2(ph.a), pm = __half22float2(ph.b);
            const float2 ql = __half22float2(qh.a), qm = __half22float2(qh.b);
            float4 h;
            h.x = pl.x + ql.x + b1v.x; h.y = pl.y + ql.y + b1v.y;
            h.z = pm.x + qm.x + b1v.z; h.w = pm.y + qm.y + b1v.w;
            h.x = fmaf(al0, wa0.x, h.x); h.y = fmaf(al0, wa0.y, h.y);
            h.z = fmaf(al0, wa0.z, h.z); h.w = fmaf(al0, wa0.w, h.w);
            h.x = fmaf(al1, wa1.x, h.x); h.y = fmaf(al1, wa1.y, h.y);
            h.z = fmaf(al1, wa1.z, h.z); h.w = fmaf(al1, wa1.w, h.w);
            h.x = fmaf(al2, wa2.x, h.x); h.y = fmaf(al2, wa2.y, h.y);
            h.z = fmaf(al2, wa2.z, h.z); h.w = fmaf(al2, wa2.w, h.w);
            h.x = fmaf(al3, wa3.x, h.x); h.y = fmaf(al3, wa3.y, h.y);
            h.z = fmaf(al3, wa3.z, h.z); h.w = fmaf(al3, wa3.w, h.w);
            h.x = fmaxf(h.x, 0.f); h.y = fmaxf(h.y, 0.f);
            h.z = fmaxf(h.z, 0.f); h.w = fmaxf(h.w, 0.f);

            float v0 = h.x * w2a.x + h.y * w2a.z + h.z * w2b.x + h.w * w2b.z;
            float v1 = h.x * w2a.y + h.y * w2a.w + h.z * w2b.y + h.w * w2b.w;
            #pragma unroll
            for (int msk = 1; msk < 16; msk <<= 1) {
                v0 += __shfl_xor(v0, msk, 64);
                v1 += __shfl_xor(v1, msk, 64);
            }
            if (c == 0)
                *(float2*)&out_edges[(size_t)perm[j] * 2] = make_float2(v0 + bo0, v1 + bo1);
        }
    }
}

// ================= fallback: the proven R4 multi-kernel path =================

__global__ __launch_bounds__(256) void gemm_pq_half_k(const float* __restrict__ A,
                                                      const float* __restrict__ B,
                                                      __half* __restrict__ C,
                                                      int N, int K, int M) {
    __shared__ float As[16][68];
    __shared__ float Bs[16][64];
    gemm_pq_tile(A, B, C, N, K, M, blockIdx.x * 64, blockIdx.y * 64, threadIdx.x, As, Bs);
}

template <int CH, bool HOUT>
__global__ __launch_bounds__(256) void gemm_att_k(const float* __restrict__ A,
                                                  const float* __restrict__ B,
                                                  void* __restrict__ Cv,
                                                  const float* __restrict__ att_s,
                                                  const float* __restrict__ att_d,
                                                  float* __restrict__ a_s,
                                                  float* __restrict__ a_d,
                                                  int N, int K, int M) {
    __shared__ float As[16][68];
    __shared__ float Bs[16][64];
    gemm_att_tile<CH, HOUT>(A, B, Cv, att_s, att_d, a_s, a_d, N, K, M,
                            blockIdx.x * 64, blockIdx.y * 64, threadIdx.x, As, Bs);
}

__global__ __launch_bounds__(256) void count_deg_k(const int* __restrict__ ei,
                                                   int* __restrict__ deg) {
    const int e = blockIdx.x * 256 + threadIdx.x;
    if (e < EE) atomicAdd(&deg[ei[EE + e]], 1);
}

__global__ __launch_bounds__(1024) void scan_k(const int* __restrict__ deg,
                                               int* __restrict__ rowptr,
                                               int* __restrict__ cursor) {
    __shared__ int wsum[16];
    const int tid = threadIdx.x;
    const int lane = tid & 63, wvv = tid >> 6;
    int total = 0;
    for (int base = 0; base < NN; base += 1024) {
        const int i = base + tid;
        const int v = (i < NN) ? deg[i] : 0;
        int incl = v;
        #pragma unroll
        for (int d = 1; d < 64; d <<= 1) {
            int t = __shfl_up(incl, d, 64);
            if (lane >= d) incl += t;
        }
        if (lane == 63) wsum[wvv] = incl;
        __syncthreads();
        if (wvv == 0) {
            int s = (lane < 16) ? wsum[lane] : 0;
            #pragma unroll
            for (int d = 1; d < 16; d <<= 1) {
                int t = __shfl_up(s, d, 64);
                if (lane >= d) s += t;
            }
            if (lane < 16) wsum[lane] = s;
        }
        __syncthreads();
        const int excl = total + (wvv > 0 ? wsum[wvv - 1] : 0) + incl - v;
        const int chunk = wsum[15];
        if (i < NN) { rowptr[i] = excl; cursor[i] = excl; }
        total += chunk;
        __syncthreads();
    }
    if (tid == 0) rowptr[NN] = total;
}

__global__ __launch_bounds__(256) void scatter_perm_k(const int* __restrict__ ei,
                                                      int* __restrict__ cursor,
                                                      int* __restrict__ perm,
                                                      int* __restrict__ psrc,
                                                      int* __restrict__ pdst) {
    const int e = blockIdx.x * 256 + threadIdx.x;
    if (e >= EE) return;
    const int d = ei[EE + e];
    const int p = atomicAdd(&cursor[d], 1);
    perm[p] = e;
    psrc[p] = ei[e];
    pdst[p] = d;
}

__global__ __launch_bounds__(256) void pack_w1_k(const float* __restrict__ mW1,
                                                 float* __restrict__ W1pq) {
    const int idx = blockIdx.x * 256 + threadIdx.x;
    if (idx >= 32 * 128) return;
    const int k = idx >> 7, j = idx & 127;
    W1pq[idx] = (j < 64) ? mW1[k * 64 + j] : mW1[(36 + k) * 64 + (j - 64)];
}

__global__ __launch_bounds__(256) void softagg1h_k(const int* __restrict__ rowptr,
                                                   const int* __restrict__ psrc,
                                                   const float* __restrict__ a_s,
                                                   const float* __restrict__ a_d,
                                                   const __half* __restrict__ xl,
                                                   const float* __restrict__ bias,
                                                   float* __restrict__ out) {
    const int n = blockIdx.x * 4 + (threadIdx.x >> 6);
    if (n >= NN) return;
    softagg1_node(n, threadIdx.x & 63, rowptr, psrc, a_s, a_d, xl, bias, out);
}

__global__ __launch_bounds__(256) void softagg2h_k(const int* __restrict__ rowptr,
                                                   const int* __restrict__ psrc,
                                                   const float* __restrict__ a_s,
                                                   const float* __restrict__ a_d,
                                                   float* __restrict__ alpha_p,
                                                   float* __restrict__ inv_s,
                                                   const __half* __restrict__ xl,
                                                   const float* __restrict__ bias,
                                                   float* __restrict__ out) {
    const int n = blockIdx.x * 4 + (threadIdx.x >> 6);
    if (n >= NN) return;
    softagg2_node(n, threadIdx.x & 63, rowptr, psrc, a_s, a_d, alpha_p, inv_s, xl, bias, out);
}

__global__ __launch_bounds__(256) void edge_mlp_k(const __half* __restrict__ PQ,
                                                  const float* __restrict__ alpha_p,
                                                  const float* __restrict__ inv_s,
                                                  const int* __restrict__ psrc,
                                                  const int* __restrict__ pdst,
                                                  const int* __restrict__ perm,
                                                  const float* __restrict__ mW1,
                                                  const float* __restrict__ mb1,
                                                  const float* __restrict__ mW2,
                                                  const float* __restrict__ mb2,
                                                  float* __restrict__ out) {
    const int lane = threadIdx.x & 63, wvv = threadIdx.x >> 6;
    const int g = lane >> 4, c = lane & 15;

    const float4 wa0 = *(const float4*)&mW1[32 * 64 + c * 4];
    const float4 wa1 = *(const float4*)&mW1[33 * 64 + c * 4];
    const float4 wa2 = *(const float4*)&mW1[34 * 64 + c * 4];
    const float4 wa3 = *(const float4*)&mW1[35 * 64 + c * 4];
    const float4 b1v = *(const float4*)&mb1[c * 4];
    const float4 w2a = *(const float4*)&mW2[c * 8];
    const float4 w2b = *(const float4*)&mW2[c * 8 + 4];
    const float bo0 = mb2[0], bo1 = mb2[1];

    const h4* PQ4 = (const h4*)PQ;
    const int gw = blockIdx.x * 4 + wvv;
    const int stride4 = gridDim.x * 4 * 4;

    for (int jb = gw * 4; jb < EE; jb += stride4) {
        const int j = jb + g;
        const int s = psrc[j];
        const int d = pdst[j];
        const float4 ar = *(const float4*)&alpha_p[(size_t)j * 4];
        const float4 iv = *(const float4*)&inv_s[(size_t)d * 4];
        const float al0 = ar.x * iv.x, al1 = ar.y * iv.y;
        const float al2 = ar.z * iv.z, al3 = ar.w * iv.w;
        const h4 ph = PQ4[(size_t)s * 32 + c];
        const h4 qh = PQ4[(size_t)d * 32 + 16 + c];
        const float2 pl = __half22float2(ph.a), pm = __half22float2(ph.b);
        const float2 ql = __half22float2(qh.a), qm = __half22float2(qh.b);
        float4 h;
        h.x = pl.x + ql.x + b1v.x; h.y = pl.y + ql.y + b1v.y;
        h.z = pm.x + qm.x + b1v.z; h.w = pm.y + qm.y + b1v.w;
        h.x = fmaf(al0, wa0.x, h.x); h.y = fmaf(al0, wa0.y, h.y);
        h.z = fmaf(al0, wa0.z, h.z); h.w = fmaf(al0, wa0.w, h.w);
        h.x = fmaf(al1, wa1.x, h.x); h.y = fmaf(al1, wa1.y, h.y);
        h.z = fmaf(al1, wa1.z, h.z); h.w = fmaf(al1, wa1.w, h.w);
        h.x = fmaf(al2, wa2.x, h.x); h.y = fmaf(al2, wa2.y, h.y);
        h.z = fmaf(al2, wa2.z, h.z); h.w = fmaf(al2, wa2.w, h.w);
        h.x = fmaf(al3, wa3.x, h.x); h.y = fmaf(al3, wa3.y, h.y);
        h.z = fmaf(al3, wa3.z, h.z); h.w = fmaf(al3, wa3.w, h.w);
        h.x = fmaxf(h.x, 0.f); h.y = fmaxf(h.y, 0.f);
        h.z = fmaxf(h.z, 0.f); h.w = fmaxf(h.w, 0.f);

        float v0 = h.x * w2a.x + h.y * w2a.z + h.z * w2b.x + h.w * w2b.z;
        float v1 = h.x * w2a.y + h.y * w2a.w + h.z * w2b.y + h.w * w2b.w;
        #pragma unroll
        for (int msk = 1; msk < 16; msk <<= 1) {
            v0 += __shfl_xor(v0, msk, 64);
            v1 += __shfl_xor(v1, msk, 64);
        }
        if (c == 0)
            *(float2*)&out[(size_t)perm[j] * 2] = make_float2(v0 + bo0, v1 + bo1);
    }
}

extern "C" void kernel_launch(void* const* d_in, const int* in_sizes, int n_in,
                              void* d_out, int out_size, void* d_ws, size_t ws_size,
                              hipStream_t stream) {
    const float* x        = (const float*)d_in[0];
    const int*   ei       = (const int*)d_in[1];
    // d_in[2] edge_attr: unused (edge_dim=None). d_in[3] flag: unused.
    const float* W1       = (const float*)d_in[4];
    const float* att1_src = (const float*)d_in[5];
    const float* att1_dst = (const float*)d_in[6];
    const float* b1       = (const float*)d_in[7];
    const float* W3       = (const float*)d_in[8];
    const float* att3_src = (const float*)d_in[9];
    const float* att3_dst = (const float*)d_in[10];
    const float* b3       = (const float*)d_in[11];
    const float* mW1      = (const float*)d_in[12];
    const float* mb1      = (const float*)d_in[13];
    const float* mW2      = (const float*)d_in[14];
    const float* mb2      = (const float*)d_in[15];

    float* out_nodes = (float*)d_out;               // [N,32]
    float* out_edges = out_nodes + (size_t)NN * 32; // [E,2]

    // workspace layout (floats/ints)
    float* ws = (float*)d_ws;
    __half*   xlh     = (__half*)ws;                  // N*256 halves (layer-1 GEMM out)
    __half*   xl2h    = (__half*)ws;                  // N*128 halves (layer-2 GEMM out)
    __half*   PQh     = (__half*)ws;                  // N*128 halves, after xl2h dead
    float*    h1      = ws + 12800000;                // N*64
    float*    alpha_p = ws + 16000000;                // E*4 (CSR-order raw w, layer 2)
    float*    a_s     = ws + 25600000;                // N*4
    float*    a_d     = ws + 25800000;                // N*4
    float*    W1pq    = ws + 26000000;                // 32*128
    float*    inv_s   = ws + 26100000;                // N*4
    int*      bsum    = (int*)(ws + 26300000);        // NCH (196)
    int*      boff    = (int*)(ws + 26301000);        // NCH
    int*      deg     = (int*)(ws + 26400000);        // N
    int*      cursor  = (int*)(ws + 26450000);        // N
    int*      rowptr  = (int*)(ws + 26500000);        // N+1
    int*      perm    = (int*)(ws + 26550008);        // E
    int*      psrc    = (int*)(ws + 27350008);        // E
    int*      pdst    = (int*)(ws + 28150008);        // E

    // ---- Attempt single cooperative persistent kernel ----
    static int coopGrid = -1;
    if (coopGrid < 0) {
        int maxB = 0;
        hipError_t qe = hipOccupancyMaxActiveBlocksPerMultiprocessor(&maxB, fused_gat, 256, 0);
        if (qe == hipSuccess && maxB >= 1) {
            int g = maxB * 256;            // 256 CUs on MI355X
            if (g > 2048) g = 2048;
            coopGrid = g;
        } else {
            coopGrid = 0;
        }
    }

    if (coopGrid > 0) {
        void* args[] = {
            (void*)&x, (void*)&ei,
            (void*)&W1, (void*)&att1_src, (void*)&att1_dst, (void*)&b1,
            (void*)&W3, (void*)&att3_src, (void*)&att3_dst, (void*)&b3,
            (void*)&mW1, (void*)&mb1, (void*)&mW2, (void*)&mb2,
            (void*)&out_nodes, (void*)&out_edges,
            (void*)&xlh, (void*)&h1, (void*)&xl2h, (void*)&PQh,
            (void*)&alpha_p, (void*)&a_s, (void*)&a_d, (void*)&W1pq, (void*)&inv_s,
            (void*)&deg, (void*)&cursor, (void*)&rowptr,
            (void*)&perm, (void*)&psrc, (void*)&pdst,
            (void*)&bsum, (void*)&boff};
        hipError_t le = hipLaunchCooperativeKernel(fused_gat, dim3(coopGrid), dim3(256),
                                                   args, 0, stream);
        if (le == hipSuccess) return;
        coopGrid = 0;   // fall through to the proven multi-kernel path
    }

    // ---- Fallback: R4 multi-kernel path ----
    const int gemmRows = GEMM_ROWS;       // 782
    const int EB = (EE + 255) / 256;      // 3125
    const int NB4 = (NN + 3) / 4;

    hipMemsetAsync(deg, 0, (size_t)NN * 4, stream);
    count_deg_k<<<EB, 256, 0, stream>>>(ei, deg);
    scan_k<<<1, 1024, 0, stream>>>(deg, rowptr, cursor);
    scatter_perm_k<<<EB, 256, 0, stream>>>(ei, cursor, perm, psrc, pdst);
    pack_w1_k<<<16, 256, 0, stream>>>(mW1, W1pq);

    gemm_att_k<64, true><<<dim3(gemmRows, 4), 256, 0, stream>>>(x, W1, xlh, att1_src, att1_dst,
                                                                a_s, a_d, NN, INF, NH * 64);
    softagg1h_k<<<NB4, 256, 0, stream>>>(rowptr, psrc, a_s, a_d, xlh, b1, h1);

    gemm_att_k<32, true><<<dim3(gemmRows, 2), 256, 0, stream>>>(h1, W3, xl2h, att3_src, att3_dst,
                                                                a_s, a_d, NN, 64, NH * 32);
    softagg2h_k<<<NB4, 256, 0, stream>>>(rowptr, psrc, a_s, a_d, alpha_p, inv_s, xl2h, b3,
                                         out_nodes);

    gemm_pq_half_k<<<dim3(gemmRows, 2), 256, 0, stream>>>(out_nodes, W1pq, PQh, NN, 32, 128);
    edge_mlp_k<<<2048, 256, 0, stream>>>(PQh, alpha_p, inv_s, psrc, pdst, perm,
                                         mW1, mb1, mW2, mb2, out_edges);
}

// Round 6
// 480.275 us; speedup vs baseline: 2.5388x; 2.5388x over previous
//
#include <hip/hip_runtime.h>
#include <hip/hip_fp16.h>

// Problem constants
constexpr int NN   = 50000;
constexpr int EE   = 800000;
constexpr int INF  = 128;   // input feat
constexpr int NH   = 4;     // heads
constexpr int GEMM_ROWS = (NN + 63) / 64;   // 782
constexpr int EB   = (EE + 255) / 256;      // 3125 edge blocks

struct __align__(8) h4 { __half2 a, b; };   // 4 halves = 8 bytes

__device__ __forceinline__ float elw(float a) {
    a = (a > 0.f) ? a : 0.2f * a;          // leaky_relu(0.2)
    return __expf(a);                       // exp without max-sub (scores bounded)
}

// ================= device helpers (bodies identical to proven R4 kernels) =================

template <int CH, bool HOUT>
__device__ __forceinline__ void gemm_att_tile(const float* __restrict__ A,
                                              const float* __restrict__ B,
                                              void* __restrict__ Cv,
                                              const float* __restrict__ att_s,
                                              const float* __restrict__ att_d,
                                              float* __restrict__ a_s,
                                              float* __restrict__ a_d,
                                              int N, int K, int M,
                                              int row0, int col0, int tid,
                                              float (*As)[68], float (*Bs)[64]) {
    const int tx = tid & 15, ty = tid >> 4;
    const int col  = col0 + tx * 4;
    const int head = col / CH;
    const int pos  = col % CH;
    float attS[4], attD[4];
    #pragma unroll
    for (int j = 0; j < 4; ++j) {
        attS[j] = att_s[head * CH + pos + j];
        attD[j] = att_d[head * CH + pos + j];
    }
    float acc[4][4] = {};
    for (int k0 = 0; k0 < K; k0 += 16) {
        {
            const int a_row = tid >> 2;
            const int a_k   = (tid & 3) * 4;
            const int gr    = row0 + a_row;
            float4 v = make_float4(0.f, 0.f, 0.f, 0.f);
            if (gr < N) v = *(const float4*)(A + (size_t)gr * K + k0 + a_k);
            As[a_k + 0][a_row] = v.x;
            As[a_k + 1][a_row] = v.y;
            As[a_k + 2][a_row] = v.z;
            As[a_k + 3][a_row] = v.w;
        }
        {
            const int b_k = tid >> 4;
            const int b_c = (tid & 15) * 4;
            float4 w = *(const float4*)(B + (size_t)(k0 + b_k) * M + col0 + b_c);
            *(float4*)&Bs[b_k][b_c] = w;
        }
        __syncthreads();
        #pragma unroll
        for (int kk = 0; kk < 16; ++kk) {
            float4 a = *(const float4*)&As[kk][ty * 4];
            float4 b = *(const float4*)&Bs[kk][tx * 4];
            const float av[4] = {a.x, a.y, a.z, a.w};
            const float bv[4] = {b.x, b.y, b.z, b.w};
            #pragma unroll
            for (int i = 0; i < 4; ++i)
                #pragma unroll
                for (int j = 0; j < 4; ++j)
                    acc[i][j] = fmaf(av[i], bv[j], acc[i][j]);
        }
        __syncthreads();
    }
    #pragma unroll
    for (int i = 0; i < 4; ++i) {
        const int r = row0 + ty * 4 + i;
        if (r < N) {
            if constexpr (HOUT) {
                __half* C  = (__half*)Cv;
                __half* cp = C + (size_t)r * M + col0 + tx * 4;
                __half2 q0 = __halves2half2(__float2half_rn(acc[i][0]), __float2half_rn(acc[i][1]));
                __half2 q1 = __halves2half2(__float2half_rn(acc[i][2]), __float2half_rn(acc[i][3]));
                *(__half2*)cp       = q0;
                *(__half2*)(cp + 2) = q1;
            } else {
                float* C  = (float*)Cv;
                float* cp = C + (size_t)r * M + col0 + tx * 4;
                cp[0] = acc[i][0]; cp[1] = acc[i][1]; cp[2] = acc[i][2]; cp[3] = acc[i][3];
            }
        }
        float ss = 0.f, sd = 0.f;
        #pragma unroll
        for (int j = 0; j < 4; ++j) {
            ss = fmaf(acc[i][j], attS[j], ss);
            sd = fmaf(acc[i][j], attD[j], sd);
        }
        #pragma unroll
        for (int msk = 1; msk < CH / 4; msk <<= 1) {
            ss += __shfl_xor(ss, msk, 64);
            sd += __shfl_xor(sd, msk, 64);
        }
        if ((tx & (CH / 4 - 1)) == 0 && r < N) {
            a_s[r * NH + head] = ss;
            a_d[r * NH + head] = sd;
        }
    }
}

__device__ __forceinline__ void gemm_pq_tile(const float* __restrict__ A,
                                             const float* __restrict__ B,
                                             __half* __restrict__ C,
                                             int N, int K, int M,
                                             int row0, int col0, int tid,
                                             float (*As)[68], float (*Bs)[64]) {
    const int tx = tid & 15, ty = tid >> 4;
    float acc[4][4] = {};
    for (int k0 = 0; k0 < K; k0 += 16) {
        {
            const int a_row = tid >> 2;
            const int a_k   = (tid & 3) * 4;
            const int gr    = row0 + a_row;
            float4 v = make_float4(0.f, 0.f, 0.f, 0.f);
            if (gr < N) v = *(const float4*)(A + (size_t)gr * K + k0 + a_k);
            As[a_k + 0][a_row] = v.x;
            As[a_k + 1][a_row] = v.y;
            As[a_k + 2][a_row] = v.z;
            As[a_k + 3][a_row] = v.w;
        }
        {
            const int b_k = tid >> 4;
            const int b_c = (tid & 15) * 4;
            float4 w = *(const float4*)(B + (size_t)(k0 + b_k) * M + col0 + b_c);
            *(float4*)&Bs[b_k][b_c] = w;
        }
        __syncthreads();
        #pragma unroll
        for (int kk = 0; kk < 16; ++kk) {
            float4 a = *(const float4*)&As[kk][ty * 4];
            float4 b = *(const float4*)&Bs[kk][tx * 4];
            const float av[4] = {a.x, a.y, a.z, a.w};
            const float bv[4] = {b.x, b.y, b.z, b.w};
            #pragma unroll
            for (int i = 0; i < 4; ++i)
                #pragma unroll
                for (int j = 0; j < 4; ++j)
                    acc[i][j] = fmaf(av[i], bv[j], acc[i][j]);
        }
        __syncthreads();
    }
    #pragma unroll
    for (int i = 0; i < 4; ++i) {
        const int r = row0 + ty * 4 + i;
        if (r < N) {
            __half* cp = C + (size_t)r * M + col0 + tx * 4;
            __half2 q0 = __halves2half2(__float2half_rn(acc[i][0]), __float2half_rn(acc[i][1]));
            __half2 q1 = __halves2half2(__float2half_rn(acc[i][2]), __float2half_rn(acc[i][3]));
            *(__half2*)cp       = q0;
            *(__half2*)(cp + 2) = q1;
        }
    }
}

__device__ __forceinline__ void softagg1_node(int n, int lane,
                                              const int* __restrict__ rowptr,
                                              const int* __restrict__ psrc,
                                              const float* __restrict__ a_s,
                                              const float* __restrict__ a_d,
                                              const __half* __restrict__ xl,
                                              const float* __restrict__ bias,
                                              float* __restrict__ out) {
    const int r0 = rowptr[n], r1 = rowptr[n + 1];
    const int hh = lane >> 4;
    const float ad = a_d[n * NH + hh];

    const h4* X = (const h4*)xl;   // row stride 64 h4 units (256 halves)
    float4 A0 = {0,0,0,0}, A1 = {0,0,0,0}, A2 = {0,0,0,0}, A3 = {0,0,0,0};
    float sum = 0.f;
    int j = r0;
    for (; j + 7 < r1; j += 8) {
        const int s0 = psrc[j],     s1 = psrc[j + 1], s2 = psrc[j + 2], s3 = psrc[j + 3];
        const int s4 = psrc[j + 4], s5 = psrc[j + 5], s6 = psrc[j + 6], s7 = psrc[j + 7];
        const float w0 = elw(a_s[s0 * NH + hh] + ad);
        const float w1 = elw(a_s[s1 * NH + hh] + ad);
        const float w2 = elw(a_s[s2 * NH + hh] + ad);
        const float w3 = elw(a_s[s3 * NH + hh] + ad);
        const float w4 = elw(a_s[s4 * NH + hh] + ad);
        const float w5 = elw(a_s[s5 * NH + hh] + ad);
        const float w6 = elw(a_s[s6 * NH + hh] + ad);
        const float w7 = elw(a_s[s7 * NH + hh] + ad);
        sum += ((w0 + w1) + (w2 + w3)) + ((w4 + w5) + (w6 + w7));
        const h4 v0 = X[(size_t)s0 * 64 + lane];
        const h4 v1 = X[(size_t)s1 * 64 + lane];
        const h4 v2 = X[(size_t)s2 * 64 + lane];
        const h4 v3 = X[(size_t)s3 * 64 + lane];
        const h4 v4 = X[(size_t)s4 * 64 + lane];
        const h4 v5 = X[(size_t)s5 * 64 + lane];
        const h4 v6 = X[(size_t)s6 * 64 + lane];
        const h4 v7 = X[(size_t)s7 * 64 + lane];
        float2 l0 = __half22float2(v0.a), m0 = __half22float2(v0.b);
        float2 l1 = __half22float2(v1.a), m1 = __half22float2(v1.b);
        float2 l2 = __half22float2(v2.a), m2 = __half22float2(v2.b);
        float2 l3 = __half22float2(v3.a), m3 = __half22float2(v3.b);
        float2 l4 = __half22float2(v4.a), m4 = __half22float2(v4.b);
        float2 l5 = __half22float2(v5.a), m5 = __half22float2(v5.b);
        float2 l6 = __half22float2(v6.a), m6 = __half22float2(v6.b);
        float2 l7 = __half22float2(v7.a), m7 = __half22float2(v7.b);
        A0.x = fmaf(w0, l0.x, A0.x); A0.y = fmaf(w0, l0.y, A0.y);
        A0.z = fmaf(w0, m0.x, A0.z); A0.w = fmaf(w0, m0.y, A0.w);
        A1.x = fmaf(w1, l1.x, A1.x); A1.y = fmaf(w1, l1.y, A1.y);
        A1.z = fmaf(w1, m1.x, A1.z); A1.w = fmaf(w1, m1.y, A1.w);
        A2.x = fmaf(w2, l2.x, A2.x); A2.y = fmaf(w2, l2.y, A2.y);
        A2.z = fmaf(w2, m2.x, A2.z); A2.w = fmaf(w2, m2.y, A2.w);
        A3.x = fmaf(w3, l3.x, A3.x); A3.y = fmaf(w3, l3.y, A3.y);
        A3.z = fmaf(w3, m3.x, A3.z); A3.w = fmaf(w3, m3.y, A3.w);
        A0.x = fmaf(w4, l4.x, A0.x); A0.y = fmaf(w4, l4.y, A0.y);
        A0.z = fmaf(w4, m4.x, A0.z); A0.w = fmaf(w4, m4.y, A0.w);
        A1.x = fmaf(w5, l5.x, A1.x); A1.y = fmaf(w5, l5.y, A1.y);
        A1.z = fmaf(w5, m5.x, A1.z); A1.w = fmaf(w5, m5.y, A1.w);
        A2.x = fmaf(w6, l6.x, A2.x); A2.y = fmaf(w6, l6.y, A2.y);
        A2.z = fmaf(w6, m6.x, A2.z); A2.w = fmaf(w6, m6.y, A2.w);
        A3.x = fmaf(w7, l7.x, A3.x); A3.y = fmaf(w7, l7.y, A3.y);
        A3.z = fmaf(w7, m7.x, A3.z); A3.w = fmaf(w7, m7.y, A3.w);
    }
    for (; j < r1; ++j) {
        const int s0 = psrc[j];
        const float w0 = elw(a_s[s0 * NH + hh] + ad);
        sum += w0;
        const h4 v0 = X[(size_t)s0 * 64 + lane];
        float2 l0 = __half22float2(v0.a), m0 = __half22float2(v0.b);
        A0.x = fmaf(w0, l0.x, A0.x); A0.y = fmaf(w0, l0.y, A0.y);
        A0.z = fmaf(w0, m0.x, A0.z); A0.w = fmaf(w0, m0.y, A0.w);
    }
    const float inv = 1.f / (sum + 1e-30f);
    float4 t;
    t.x = ((A0.x + A1.x) + (A2.x + A3.x)) * inv;
    t.y = ((A0.y + A1.y) + (A2.y + A3.y)) * inv;
    t.z = ((A0.z + A1.z) + (A2.z + A3.z)) * inv;
    t.w = ((A0.w + A1.w) + (A2.w + A3.w)) * inv;
    #pragma unroll
    for (int msk = 16; msk < 64; msk <<= 1) {
        t.x += __shfl_xor(t.x, msk, 64);
        t.y += __shfl_xor(t.y, msk, 64);
        t.z += __shfl_xor(t.z, msk, 64);
        t.w += __shfl_xor(t.w, msk, 64);
    }
    if (lane < 16) {
        const float4 b = ((const float4*)bias)[lane];
        float4 o;
        o.x = t.x * 0.25f + b.x; o.y = t.y * 0.25f + b.y;
        o.z = t.z * 0.25f + b.z; o.w = t.w * 0.25f + b.w;
        ((float4*)out)[(size_t)n * 16 + lane] = o;
    }
}

__device__ __forceinline__ void softagg2_node(int n, int lane,
                                              const int* __restrict__ rowptr,
                                              const int* __restrict__ psrc,
                                              const float* __restrict__ a_s,
                                              const float* __restrict__ a_d,
                                              float* __restrict__ alpha_p,
                                              float* __restrict__ inv_s,
                                              const __half* __restrict__ xl,
                                              const float* __restrict__ bias,
                                              float* __restrict__ out) {
    const int r0 = rowptr[n], r1 = rowptr[n + 1];
    const int cl = lane & 31, half = lane >> 5, hh = cl >> 3;
    const float ad = a_d[n * NH + hh];
    const bool writer = (cl & 7) == 0;   // one lane per (half, head) writes raw w

    const h4* X = (const h4*)xl;   // row stride 32 h4 units (128 halves)
    float4 A0 = {0,0,0,0}, A1 = {0,0,0,0};
    float sum = 0.f;
    int j = r0;
    for (; j + 7 < r1; j += 8) {
        const int ja = j + half, jc = j + 2 + half, je = j + 4 + half, jg = j + 6 + half;
        const int sa = psrc[ja], sc = psrc[jc], se = psrc[je], sg = psrc[jg];
        const float wa = elw(a_s[sa * NH + hh] + ad);
        const float wc = elw(a_s[sc * NH + hh] + ad);
        const float we = elw(a_s[se * NH + hh] + ad);
        const float wg = elw(a_s[sg * NH + hh] + ad);
        if (writer) {
            alpha_p[ja * NH + hh] = wa; alpha_p[jc * NH + hh] = wc;
            alpha_p[je * NH + hh] = we; alpha_p[jg * NH + hh] = wg;
        }
        sum += (wa + wc) + (we + wg);
        const h4 va = X[(size_t)sa * 32 + cl];
        const h4 vc = X[(size_t)sc * 32 + cl];
        const h4 ve = X[(size_t)se * 32 + cl];
        const h4 vg = X[(size_t)sg * 32 + cl];
        const float2 la = __half22float2(va.a), ma = __half22float2(va.b);
        const float2 lc = __half22float2(vc.a), mc = __half22float2(vc.b);
        const float2 le = __half22float2(ve.a), me = __half22float2(ve.b);
        const float2 lg = __half22float2(vg.a), mg = __half22float2(vg.b);
        A0.x = fmaf(wa, la.x, A0.x); A0.y = fmaf(wa, la.y, A0.y);
        A0.z = fmaf(wa, ma.x, A0.z); A0.w = fmaf(wa, ma.y, A0.w);
        A1.x = fmaf(wc, lc.x, A1.x); A1.y = fmaf(wc, lc.y, A1.y);
        A1.z = fmaf(wc, mc.x, A1.z); A1.w = fmaf(wc, mc.y, A1.w);
        A0.x = fmaf(we, le.x, A0.x); A0.y = fmaf(we, le.y, A0.y);
        A0.z = fmaf(we, me.x, A0.z); A0.w = fmaf(we, me.y, A0.w);
        A1.x = fmaf(wg, lg.x, A1.x); A1.y = fmaf(wg, lg.y, A1.y);
        A1.z = fmaf(wg, mg.x, A1.z); A1.w = fmaf(wg, mg.y, A1.w);
    }
    for (; j < r1; j += 2) {
        const int ja = j + half;
        const bool valid = ja < r1;
        const int sa = psrc[valid ? ja : r0];
        float wa = 0.f;
        if (valid) {
            wa = elw(a_s[sa * NH + hh] + ad);
            if (writer) alpha_p[ja * NH + hh] = wa;
        }
        sum += wa;
        const h4 va = X[(size_t)sa * 32 + cl];
        const float2 la = __half22float2(va.a), ma = __half22float2(va.b);
        A0.x = fmaf(wa, la.x, A0.x); A0.y = fmaf(wa, la.y, A0.y);
        A0.z = fmaf(wa, ma.x, A0.z); A0.w = fmaf(wa, ma.y, A0.w);
    }
    // merge halves' partial sums, then normalize
    sum += __shfl_xor(sum, 32, 64);
    const float inv = 1.f / (sum + 1e-30f);
    if (writer && half == 0) inv_s[n * NH + hh] = inv;

    float4 t;
    t.x = A0.x + A1.x; t.y = A0.y + A1.y; t.z = A0.z + A1.z; t.w = A0.w + A1.w;
    t.x += __shfl_xor(t.x, 32, 64);
    t.y += __shfl_xor(t.y, 32, 64);
    t.z += __shfl_xor(t.z, 32, 64);
    t.w += __shfl_xor(t.w, 32, 64);
    t.x *= inv; t.y *= inv; t.z *= inv; t.w *= inv;
    #pragma unroll
    for (int q = 0; q < 2; ++q) {
        const int msk = (q == 0) ? 8 : 16;
        t.x += __shfl_xor(t.x, msk, 64);
        t.y += __shfl_xor(t.y, msk, 64);
        t.z += __shfl_xor(t.z, msk, 64);
        t.w += __shfl_xor(t.w, msk, 64);
    }
    if (lane < 8) {
        const float4 b = ((const float4*)bias)[lane];
        float4 o;
        o.x = t.x * 0.25f + b.x; o.y = t.y * 0.25f + b.y;
        o.z = t.z * 0.25f + b.z; o.w = t.w * 0.25f + b.w;
        ((float4*)out)[(size_t)n * 8 + lane] = o;
    }
}

// ================= kernels =================

// Fused independent stage: count_deg (blocks [0,EB)) + pack_w1 (blocks [EB,EB+16))
// + layer-1 GEMM (rest). No data dependence among the three; memset(deg) precedes
// this launch on the stream. Removes 2 launch boundaries and hides count/pack
// under the GEMM.
__global__ __launch_bounds__(256) void csr_gemm1_k(const int* __restrict__ ei,
                                                   int* __restrict__ deg,
                                                   const float* __restrict__ mW1,
                                                   float* __restrict__ W1pq,
                                                   const float* __restrict__ x,
                                                   const float* __restrict__ W1,
                                                   __half* __restrict__ xlh,
                                                   const float* __restrict__ att1s,
                                                   const float* __restrict__ att1d,
                                                   float* __restrict__ a_s,
                                                   float* __restrict__ a_d) {
    __shared__ float As[16][68];
    __shared__ float Bs[16][64];
    const int b = blockIdx.x;
    if (b < EB) {
        const int e = b * 256 + threadIdx.x;
        if (e < EE) atomicAdd(&deg[ei[EE + e]], 1);
    } else if (b < EB + 16) {
        const int idx = (b - EB) * 256 + threadIdx.x;   // 32*128 = 4096 elems
        if (idx < 32 * 128) {
            const int k = idx >> 7, jj = idx & 127;
            W1pq[idx] = (jj < 64) ? mW1[k * 64 + jj] : mW1[(36 + k) * 64 + (jj - 64)];
        }
    } else {
        const int t = b - EB - 16;                      // [0, GEMM_ROWS*4)
        gemm_att_tile<64, true>(x, W1, xlh, att1s, att1d, a_s, a_d,
                                NN, INF, NH * 64,
                                (t % GEMM_ROWS) * 64, (t / GEMM_ROWS) * 64,
                                threadIdx.x, As, Bs);
    }
}

__global__ __launch_bounds__(1024) void scan_k(const int* __restrict__ deg,
                                               int* __restrict__ rowptr,
                                               int* __restrict__ cursor) {
    __shared__ int wsum[16];
    const int tid = threadIdx.x;
    const int lane = tid & 63, wvv = tid >> 6;
    int total = 0;
    for (int base = 0; base < NN; base += 1024) {
        const int i = base + tid;
        const int v = (i < NN) ? deg[i] : 0;
        int incl = v;
        #pragma unroll
        for (int d = 1; d < 64; d <<= 1) {
            int t = __shfl_up(incl, d, 64);
            if (lane >= d) incl += t;
        }
        if (lane == 63) wsum[wvv] = incl;
        __syncthreads();
        if (wvv == 0) {
            int s = (lane < 16) ? wsum[lane] : 0;
            #pragma unroll
            for (int d = 1; d < 16; d <<= 1) {
                int t = __shfl_up(s, d, 64);
                if (lane >= d) s += t;
            }
            if (lane < 16) wsum[lane] = s;
        }
        __syncthreads();
        const int excl = total + (wvv > 0 ? wsum[wvv - 1] : 0) + incl - v;
        const int chunk = wsum[15];
        if (i < NN) { rowptr[i] = excl; cursor[i] = excl; }
        total += chunk;
        __syncthreads();
    }
    if (tid == 0) rowptr[NN] = total;
}

__global__ __launch_bounds__(256) void scatter_perm_k(const int* __restrict__ ei,
                                                      int* __restrict__ cursor,
                                                      int* __restrict__ perm,
                                                      int* __restrict__ psrc,
                                                      int* __restrict__ pdst) {
    const int e = blockIdx.x * 256 + threadIdx.x;
    if (e >= EE) return;
    const int d = ei[EE + e];
    const int p = atomicAdd(&cursor[d], 1);
    perm[p] = e;
    psrc[p] = ei[e];
    pdst[p] = d;
}

template <int CH, bool HOUT>
__global__ __launch_bounds__(256) void gemm_att_k(const float* __restrict__ A,
                                                  const float* __restrict__ B,
                                                  void* __restrict__ Cv,
                                                  const float* __restrict__ att_s,
                                                  const float* __restrict__ att_d,
                                                  float* __restrict__ a_s,
                                                  float* __restrict__ a_d,
                                                  int N, int K, int M) {
    __shared__ float As[16][68];
    __shared__ float Bs[16][64];
    gemm_att_tile<CH, HOUT>(A, B, Cv, att_s, att_d, a_s, a_d, N, K, M,
                            blockIdx.x * 64, blockIdx.y * 64, threadIdx.x, As, Bs);
}

__global__ __launch_bounds__(256) void gemm_pq_half_k(const float* __restrict__ A,
                                                      const float* __restrict__ B,
                                                      __half* __restrict__ C,
                                                      int N, int K, int M) {
    __shared__ float As[16][68];
    __shared__ float Bs[16][64];
    gemm_pq_tile(A, B, C, N, K, M, blockIdx.x * 64, blockIdx.y * 64, threadIdx.x, As, Bs);
}

__global__ __launch_bounds__(256) void softagg1h_k(const int* __restrict__ rowptr,
                                                   const int* __restrict__ psrc,
                                                   const float* __restrict__ a_s,
                                                   const float* __restrict__ a_d,
                                                   const __half* __restrict__ xl,
                                                   const float* __restrict__ bias,
                                                   float* __restrict__ out) {
    const int n = blockIdx.x * 4 + (threadIdx.x >> 6);
    if (n >= NN) return;
    softagg1_node(n, threadIdx.x & 63, rowptr, psrc, a_s, a_d, xl, bias, out);
}

__global__ __launch_bounds__(256) void softagg2h_k(const int* __restrict__ rowptr,
                                                   const int* __restrict__ psrc,
                                                   const float* __restrict__ a_s,
                                                   const float* __restrict__ a_d,
                                                   float* __restrict__ alpha_p,
                                                   float* __restrict__ inv_s,
                                                   const __half* __restrict__ xl,
                                                   const float* __restrict__ bias,
                                                   float* __restrict__ out) {
    const int n = blockIdx.x * 4 + (threadIdx.x >> 6);
    if (n >= NN) return;
    softagg2_node(n, threadIdx.x & 63, rowptr, psrc, a_s, a_d, alpha_p, inv_s, xl, bias, out);
}

__global__ __launch_bounds__(256) void edge_mlp_k(const __half* __restrict__ PQ,
                                                  const float* __restrict__ alpha_p,
                                                  const float* __restrict__ inv_s,
                                                  const int* __restrict__ psrc,
                                                  const int* __restrict__ pdst,
                                                  const int* __restrict__ perm,
                                                  const float* __restrict__ mW1,
                                                  const float* __restrict__ mb1,
                                                  const float* __restrict__ mW2,
                                                  const float* __restrict__ mb2,
                                                  float* __restrict__ out) {
    const int lane = threadIdx.x & 63, wvv = threadIdx.x >> 6;
    const int g = lane >> 4, c = lane & 15;

    const float4 wa0 = *(const float4*)&mW1[32 * 64 + c * 4];
    const float4 wa1 = *(const float4*)&mW1[33 * 64 + c * 4];
    const float4 wa2 = *(const float4*)&mW1[34 * 64 + c * 4];
    const float4 wa3 = *(const float4*)&mW1[35 * 64 + c * 4];
    const float4 b1v = *(const float4*)&mb1[c * 4];
    const float4 w2a = *(const float4*)&mW2[c * 8];
    const float4 w2b = *(const float4*)&mW2[c * 8 + 4];
    const float bo0 = mb2[0], bo1 = mb2[1];

    const h4* PQ4 = (const h4*)PQ;
    const int gw = blockIdx.x * 4 + wvv;
    const int stride4 = gridDim.x * 4 * 4;

    for (int jb = gw * 4; jb < EE; jb += stride4) {
        const int j = jb + g;
        const int s = psrc[j];
        const int d = pdst[j];
        const float4 ar = *(const float4*)&alpha_p[(size_t)j * 4];
        const float4 iv = *(const float4*)&inv_s[(size_t)d * 4];
        const float al0 = ar.x * iv.x, al1 = ar.y * iv.y;
        const float al2 = ar.z * iv.z, al3 = ar.w * iv.w;
        const h4 ph = PQ4[(size_t)s * 32 + c];
        const h4 qh = PQ4[(size_t)d * 32 + 16 + c];
        const float2 pl = __half22float2(ph.a), pm = __half22float2(ph.b);
        const float2 ql = __half22float2(qh.a), qm = __half22float2(qh.b);
        float4 h;
        h.x = pl.x + ql.x + b1v.x; h.y = pl.y + ql.y + b1v.y;
        h.z = pm.x + qm.x + b1v.z; h.w = pm.y + qm.y + b1v.w;
        h.x = fmaf(al0, wa0.x, h.x); h.y = fmaf(al0, wa0.y, h.y);
        h.z = fmaf(al0, wa0.z, h.z); h.w = fmaf(al0, wa0.w, h.w);
        h.x = fmaf(al1, wa1.x, h.x); h.y = fmaf(al1, wa1.y, h.y);
        h.z = fmaf(al1, wa1.z, h.z); h.w = fmaf(al1, wa1.w, h.w);
        h.x = fmaf(al2, wa2.x, h.x); h.y = fmaf(al2, wa2.y, h.y);
        h.z = fmaf(al2, wa2.z, h.z); h.w = fmaf(al2, wa2.w, h.w);
        h.x = fmaf(al3, wa3.x, h.x); h.y = fmaf(al3, wa3.y, h.y);
        h.z = fmaf(al3, wa3.z, h.z); h.w = fmaf(al3, wa3.w, h.w);
        h.x = fmaxf(h.x, 0.f); h.y = fmaxf(h.y, 0.f);
        h.z = fmaxf(h.z, 0.f); h.w = fmaxf(h.w, 0.f);

        float v0 = h.x * w2a.x + h.y * w2a.z + h.z * w2b.x + h.w * w2b.z;
        float v1 = h.x * w2a.y + h.y * w2a.w + h.z * w2b.y + h.w * w2b.w;
        #pragma unroll
        for (int msk = 1; msk < 16; msk <<= 1) {
            v0 += __shfl_xor(v0, msk, 64);
            v1 += __shfl_xor(v1, msk, 64);
        }
        if (c == 0)
            *(float2*)&out[(size_t)perm[j] * 2] = make_float2(v0 + bo0, v1 + bo1);
    }
}

extern "C" void kernel_launch(void* const* d_in, const int* in_sizes, int n_in,
                              void* d_out, int out_size, void* d_ws, size_t ws_size,
                              hipStream_t stream) {
    const float* x        = (const float*)d_in[0];
    const int*   ei       = (const int*)d_in[1];
    // d_in[2] edge_attr: unused (edge_dim=None). d_in[3] flag: unused.
    const float* W1       = (const float*)d_in[4];
    const float* att1_src = (const float*)d_in[5];
    const float* att1_dst = (const float*)d_in[6];
    const float* b1       = (const float*)d_in[7];
    const float* W3       = (const float*)d_in[8];
    const float* att3_src = (const float*)d_in[9];
    const float* att3_dst = (const float*)d_in[10];
    const float* b3       = (const float*)d_in[11];
    const float* mW1      = (const float*)d_in[12];
    const float* mb1      = (const float*)d_in[13];
    const float* mW2      = (const float*)d_in[14];
    const float* mb2      = (const float*)d_in[15];

    float* out_nodes = (float*)d_out;               // [N,32]
    float* out_edges = out_nodes + (size_t)NN * 32; // [E,2]

    // workspace layout (floats/ints)
    float* ws = (float*)d_ws;
    __half*   xlh     = (__half*)ws;                  // N*256 halves (layer-1 GEMM out)
    __half*   xl2h    = (__half*)ws;                  // N*128 halves (layer-2 GEMM out)
    __half*   PQh     = (__half*)ws;                  // N*128 halves, after xl2h dead
    float*    h1      = ws + 12800000;                // N*64
    float*    alpha_p = ws + 16000000;                // E*4 (CSR-order raw w, layer 2)
    float*    a_s     = ws + 25600000;                // N*4
    float*    a_d     = ws + 25800000;                // N*4
    float*    W1pq    = ws + 26000000;                // 32*128
    float*    inv_s   = ws + 26100000;                // N*4
    int*      deg     = (int*)(ws + 26400000);        // N
    int*      cursor  = (int*)(ws + 26450000);        // N
    int*      rowptr  = (int*)(ws + 26500000);        // N+1
    int*      perm    = (int*)(ws + 26550008);        // E
    int*      psrc    = (int*)(ws + 27350008);        // E
    int*      pdst    = (int*)(ws + 28150008);        // E

    const int NB4 = (NN + 3) / 4;

    // 1) zero deg
    hipMemsetAsync(deg, 0, (size_t)NN * 4, stream);
    // 2) fused: count_deg + pack_w1 + layer-1 GEMM (mutually independent)
    csr_gemm1_k<<<EB + 16 + GEMM_ROWS * 4, 256, 0, stream>>>(ei, deg, mW1, W1pq,
                                                             x, W1, xlh,
                                                             att1_src, att1_dst, a_s, a_d);
    // 3) exclusive scan -> rowptr/cursor
    scan_k<<<1, 1024, 0, stream>>>(deg, rowptr, cursor);
    // 4) scatter edges into CSR order
    scatter_perm_k<<<EB, 256, 0, stream>>>(ei, cursor, perm, psrc, pdst);
    // 5) layer-1 softmax+aggregate
    softagg1h_k<<<NB4, 256, 0, stream>>>(rowptr, psrc, a_s, a_d, xlh, b1, h1);
    // 6) layer-2 GEMM
    gemm_att_k<32, true><<<dim3(GEMM_ROWS, 2), 256, 0, stream>>>(h1, W3, xl2h,
                                                                 att3_src, att3_dst,
                                                                 a_s, a_d, NN, 64, NH * 32);
    // 7) layer-2 softmax+aggregate
    softagg2h_k<<<NB4, 256, 0, stream>>>(rowptr, psrc, a_s, a_d, alpha_p, inv_s, xl2h, b3,
                                         out_nodes);
    // 8) PQ GEMM (xl2h dead -> PQh aliases it)
    gemm_pq_half_k<<<dim3(GEMM_ROWS, 2), 256, 0, stream>>>(out_nodes, W1pq, PQh, NN, 32, 128);
    // 9) edge MLP
    edge_mlp_k<<<2048, 256, 0, stream>>>(PQh, alpha_p, inv_s, psrc, pdst, perm,
                                         mW1, mb1, mW2, mb2, out_edges);
}

// Round 7
// 452.053 us; speedup vs baseline: 2.6973x; 1.0624x over previous
//
#include <hip/hip_runtime.h>
#include <hip/hip_fp16.h>

// Problem constants
constexpr int NN   = 50000;
constexpr int EE   = 800000;
constexpr int INF  = 128;   // input feat
constexpr int NH   = 4;     // heads
constexpr int GR128 = (NN + 127) / 128;     // 391 row tiles (128-row GEMM tiling)
constexpr int EB   = (EE + 255) / 256;      // 3125 edge blocks
constexpr int NCH  = (NN + 255) / 256;      // 196 scan chunks

struct __align__(8) h4 { __half2 a, b; };   // 4 halves = 8 bytes

__device__ __forceinline__ float elw(float a) {
    a = (a > 0.f) ? a : 0.2f * a;          // leaky_relu(0.2)
    return __expf(a);                       // exp without max-sub (scores bounded)
}

// ======== 128x128 tile fp32 GEMM, 8x8 per thread (VALU-bound micro-tile) ========
// Per kk: 64 FMAs / 4 ds_read_b128 (vs 16/2 in the old 4x4) -> ~1.7x VALU efficiency.

template <int CH, bool HOUT>
__device__ __forceinline__ void gemm_att_tile8(const float* __restrict__ A,
                                               const float* __restrict__ B,
                                               void* __restrict__ Cv,
                                               const float* __restrict__ att_s,
                                               const float* __restrict__ att_d,
                                               float* __restrict__ a_s,
                                               float* __restrict__ a_d,
                                               int N, int K, int M,
                                               int row0, int col0, int tid,
                                               float (*As)[132], float (*Bs)[132]) {
    const int tx = tid & 15, ty = tid >> 4;
    float acc[8][8] = {};

    for (int k0 = 0; k0 < K; k0 += 16) {
        {
            const int a_row = tid >> 1;          // 0..127
            const int a_k   = (tid & 1) * 8;     // 0 or 8
            const int gr    = row0 + a_row;
            float4 v0 = {0.f,0.f,0.f,0.f}, v1 = {0.f,0.f,0.f,0.f};
            if (gr < N) {
                const float* ap = A + (size_t)gr * K + k0 + a_k;
                v0 = *(const float4*)ap;
                v1 = *(const float4*)(ap + 4);
            }
            As[a_k + 0][a_row] = v0.x; As[a_k + 1][a_row] = v0.y;
            As[a_k + 2][a_row] = v0.z; As[a_k + 3][a_row] = v0.w;
            As[a_k + 4][a_row] = v1.x; As[a_k + 5][a_row] = v1.y;
            As[a_k + 6][a_row] = v1.z; As[a_k + 7][a_row] = v1.w;
        }
        {
            const int b_k = tid >> 4;            // 0..15
            const int b_c = (tid & 15) * 8;
            const float* bp = B + (size_t)(k0 + b_k) * M + col0 + b_c;
            *(float4*)&Bs[b_k][b_c]     = *(const float4*)bp;
            *(float4*)&Bs[b_k][b_c + 4] = *(const float4*)(bp + 4);
        }
        __syncthreads();
        #pragma unroll
        for (int kk = 0; kk < 16; ++kk) {
            const float4 a0 = *(const float4*)&As[kk][ty * 8];
            const float4 a1 = *(const float4*)&As[kk][ty * 8 + 4];
            const float4 b0 = *(const float4*)&Bs[kk][tx * 8];
            const float4 b1 = *(const float4*)&Bs[kk][tx * 8 + 4];
            const float av[8] = {a0.x,a0.y,a0.z,a0.w,a1.x,a1.y,a1.z,a1.w};
            const float bv[8] = {b0.x,b0.y,b0.z,b0.w,b1.x,b1.y,b1.z,b1.w};
            #pragma unroll
            for (int i = 0; i < 8; ++i)
                #pragma unroll
                for (int j = 0; j < 8; ++j)
                    acc[i][j] = fmaf(av[i], bv[j], acc[i][j]);
        }
        __syncthreads();
    }

    // epilogue: store C + fused attention scores (att loaded here to cut live regs)
    const int colb = col0 + tx * 8;              // 8 cols, all within one head (8 | CH)
    const int head = colb / CH;
    const int pos  = colb % CH;
    float attS[8], attD[8];
    #pragma unroll
    for (int j = 0; j < 8; ++j) {
        attS[j] = att_s[head * CH + pos + j];
        attD[j] = att_d[head * CH + pos + j];
    }
    #pragma unroll
    for (int i = 0; i < 8; ++i) {
        const int r = row0 + ty * 8 + i;
        if (r < N) {
            if constexpr (HOUT) {
                __half* C  = (__half*)Cv;
                __half* cp = C + (size_t)r * M + colb;
                *(__half2*)(cp + 0) = __halves2half2(__float2half_rn(acc[i][0]), __float2half_rn(acc[i][1]));
                *(__half2*)(cp + 2) = __halves2half2(__float2half_rn(acc[i][2]), __float2half_rn(acc[i][3]));
                *(__half2*)(cp + 4) = __halves2half2(__float2half_rn(acc[i][4]), __float2half_rn(acc[i][5]));
                *(__half2*)(cp + 6) = __halves2half2(__float2half_rn(acc[i][6]), __float2half_rn(acc[i][7]));
            } else {
                float* C  = (float*)Cv;
                float* cp = C + (size_t)r * M + colb;
                *(float4*)cp       = make_float4(acc[i][0], acc[i][1], acc[i][2], acc[i][3]);
                *(float4*)(cp + 4) = make_float4(acc[i][4], acc[i][5], acc[i][6], acc[i][7]);
            }
        }
        float ss = 0.f, sd = 0.f;
        #pragma unroll
        for (int j = 0; j < 8; ++j) {
            ss = fmaf(acc[i][j], attS[j], ss);
            sd = fmaf(acc[i][j], attD[j], sd);
        }
        #pragma unroll
        for (int msk = 1; msk < CH / 8; msk <<= 1) {
            ss += __shfl_xor(ss, msk, 64);
            sd += __shfl_xor(sd, msk, 64);
        }
        if ((tx & (CH / 8 - 1)) == 0 && r < N) {
            a_s[r * NH + head] = ss;
            a_d[r * NH + head] = sd;
        }
    }
}

__device__ __forceinline__ void gemm_pq_tile8(const float* __restrict__ A,
                                              const float* __restrict__ B,
                                              __half* __restrict__ C,
                                              int N, int K, int M,
                                              int row0, int col0, int tid,
                                              float (*As)[132], float (*Bs)[132]) {
    const int tx = tid & 15, ty = tid >> 4;
    float acc[8][8] = {};
    for (int k0 = 0; k0 < K; k0 += 16) {
        {
            const int a_row = tid >> 1;
            const int a_k   = (tid & 1) * 8;
            const int gr    = row0 + a_row;
            float4 v0 = {0.f,0.f,0.f,0.f}, v1 = {0.f,0.f,0.f,0.f};
            if (gr < N) {
                const float* ap = A + (size_t)gr * K + k0 + a_k;
                v0 = *(const float4*)ap;
                v1 = *(const float4*)(ap + 4);
            }
            As[a_k + 0][a_row] = v0.x; As[a_k + 1][a_row] = v0.y;
            As[a_k + 2][a_row] = v0.z; As[a_k + 3][a_row] = v0.w;
            As[a_k + 4][a_row] = v1.x; As[a_k + 5][a_row] = v1.y;
            As[a_k + 6][a_row] = v1.z; As[a_k + 7][a_row] = v1.w;
        }
        {
            const int b_k = tid >> 4;
            const int b_c = (tid & 15) * 8;
            const float* bp = B + (size_t)(k0 + b_k) * M + col0 + b_c;
            *(float4*)&Bs[b_k][b_c]     = *(const float4*)bp;
            *(float4*)&Bs[b_k][b_c + 4] = *(const float4*)(bp + 4);
        }
        __syncthreads();
        #pragma unroll
        for (int kk = 0; kk < 16; ++kk) {
            const float4 a0 = *(const float4*)&As[kk][ty * 8];
            const float4 a1 = *(const float4*)&As[kk][ty * 8 + 4];
            const float4 b0 = *(const float4*)&Bs[kk][tx * 8];
            const float4 b1 = *(const float4*)&Bs[kk][tx * 8 + 4];
            const float av[8] = {a0.x,a0.y,a0.z,a0.w,a1.x,a1.y,a1.z,a1.w};
            const float bv[8] = {b0.x,b0.y,b0.z,b0.w,b1.x,b1.y,b1.z,b1.w};
            #pragma unroll
            for (int i = 0; i < 8; ++i)
                #pragma unroll
                for (int j = 0; j < 8; ++j)
                    acc[i][j] = fmaf(av[i], bv[j], acc[i][j]);
        }
        __syncthreads();
    }
    const int colb = col0 + tx * 8;
    #pragma unroll
    for (int i = 0; i < 8; ++i) {
        const int r = row0 + ty * 8 + i;
        if (r < N) {
            __half* cp = C + (size_t)r * M + colb;
            *(__half2*)(cp + 0) = __halves2half2(__float2half_rn(acc[i][0]), __float2half_rn(acc[i][1]));
            *(__half2*)(cp + 2) = __halves2half2(__float2half_rn(acc[i][2]), __float2half_rn(acc[i][3]));
            *(__half2*)(cp + 4) = __halves2half2(__float2half_rn(acc[i][4]), __float2half_rn(acc[i][5]));
            *(__half2*)(cp + 6) = __halves2half2(__float2half_rn(acc[i][6]), __float2half_rn(acc[i][7]));
        }
    }
}

// ================= softmax+aggregate device helpers (proven R4 bodies) =================

__device__ __forceinline__ void softagg1_node(int n, int lane,
                                              const int* __restrict__ rowptr,
                                              const int* __restrict__ psrc,
                                              const float* __restrict__ a_s,
                                              const float* __restrict__ a_d,
                                              const __half* __restrict__ xl,
                                              const float* __restrict__ bias,
                                              float* __restrict__ out) {
    const int r0 = rowptr[n], r1 = rowptr[n + 1];
    const int hh = lane >> 4;
    const float ad = a_d[n * NH + hh];

    const h4* X = (const h4*)xl;   // row stride 64 h4 units (256 halves)
    float4 A0 = {0,0,0,0}, A1 = {0,0,0,0}, A2 = {0,0,0,0}, A3 = {0,0,0,0};
    float sum = 0.f;
    int j = r0;
    for (; j + 7 < r1; j += 8) {
        const int s0 = psrc[j],     s1 = psrc[j + 1], s2 = psrc[j + 2], s3 = psrc[j + 3];
        const int s4 = psrc[j + 4], s5 = psrc[j + 5], s6 = psrc[j + 6], s7 = psrc[j + 7];
        const float w0 = elw(a_s[s0 * NH + hh] + ad);
        const float w1 = elw(a_s[s1 * NH + hh] + ad);
        const float w2 = elw(a_s[s2 * NH + hh] + ad);
        const float w3 = elw(a_s[s3 * NH + hh] + ad);
        const float w4 = elw(a_s[s4 * NH + hh] + ad);
        const float w5 = elw(a_s[s5 * NH + hh] + ad);
        const float w6 = elw(a_s[s6 * NH + hh] + ad);
        const float w7 = elw(a_s[s7 * NH + hh] + ad);
        sum += ((w0 + w1) + (w2 + w3)) + ((w4 + w5) + (w6 + w7));
        const h4 v0 = X[(size_t)s0 * 64 + lane];
        const h4 v1 = X[(size_t)s1 * 64 + lane];
        const h4 v2 = X[(size_t)s2 * 64 + lane];
        const h4 v3 = X[(size_t)s3 * 64 + lane];
        const h4 v4 = X[(size_t)s4 * 64 + lane];
        const h4 v5 = X[(size_t)s5 * 64 + lane];
        const h4 v6 = X[(size_t)s6 * 64 + lane];
        const h4 v7 = X[(size_t)s7 * 64 + lane];
        float2 l0 = __half22float2(v0.a), m0 = __half22float2(v0.b);
        float2 l1 = __half22float2(v1.a), m1 = __half22float2(v1.b);
        float2 l2 = __half22float2(v2.a), m2 = __half22float2(v2.b);
        float2 l3 = __half22float2(v3.a), m3 = __half22float2(v3.b);
        float2 l4 = __half22float2(v4.a), m4 = __half22float2(v4.b);
        float2 l5 = __half22float2(v5.a), m5 = __half22float2(v5.b);
        float2 l6 = __half22float2(v6.a), m6 = __half22float2(v6.b);
        float2 l7 = __half22float2(v7.a), m7 = __half22float2(v7.b);
        A0.x = fmaf(w0, l0.x, A0.x); A0.y = fmaf(w0, l0.y, A0.y);
        A0.z = fmaf(w0, m0.x, A0.z); A0.w = fmaf(w0, m0.y, A0.w);
        A1.x = fmaf(w1, l1.x, A1.x); A1.y = fmaf(w1, l1.y, A1.y);
        A1.z = fmaf(w1, m1.x, A1.z); A1.w = fmaf(w1, m1.y, A1.w);
        A2.x = fmaf(w2, l2.x, A2.x); A2.y = fmaf(w2, l2.y, A2.y);
        A2.z = fmaf(w2, m2.x, A2.z); A2.w = fmaf(w2, m2.y, A2.w);
        A3.x = fmaf(w3, l3.x, A3.x); A3.y = fmaf(w3, l3.y, A3.y);
        A3.z = fmaf(w3, m3.x, A3.z); A3.w = fmaf(w3, m3.y, A3.w);
        A0.x = fmaf(w4, l4.x, A0.x); A0.y = fmaf(w4, l4.y, A0.y);
        A0.z = fmaf(w4, m4.x, A0.z); A0.w = fmaf(w4, m4.y, A0.w);
        A1.x = fmaf(w5, l5.x, A1.x); A1.y = fmaf(w5, l5.y, A1.y);
        A1.z = fmaf(w5, m5.x, A1.z); A1.w = fmaf(w5, m5.y, A1.w);
        A2.x = fmaf(w6, l6.x, A2.x); A2.y = fmaf(w6, l6.y, A2.y);
        A2.z = fmaf(w6, m6.x, A2.z); A2.w = fmaf(w6, m6.y, A2.w);
        A3.x = fmaf(w7, l7.x, A3.x); A3.y = fmaf(w7, l7.y, A3.y);
        A3.z = fmaf(w7, m7.x, A3.z); A3.w = fmaf(w7, m7.y, A3.w);
    }
    for (; j < r1; ++j) {
        const int s0 = psrc[j];
        const float w0 = elw(a_s[s0 * NH + hh] + ad);
        sum += w0;
        const h4 v0 = X[(size_t)s0 * 64 + lane];
        float2 l0 = __half22float2(v0.a), m0 = __half22float2(v0.b);
        A0.x = fmaf(w0, l0.x, A0.x); A0.y = fmaf(w0, l0.y, A0.y);
        A0.z = fmaf(w0, m0.x, A0.z); A0.w = fmaf(w0, m0.y, A0.w);
    }
    const float inv = 1.f / (sum + 1e-30f);
    float4 t;
    t.x = ((A0.x + A1.x) + (A2.x + A3.x)) * inv;
    t.y = ((A0.y + A1.y) + (A2.y + A3.y)) * inv;
    t.z = ((A0.z + A1.z) + (A2.z + A3.z)) * inv;
    t.w = ((A0.w + A1.w) + (A2.w + A3.w)) * inv;
    #pragma unroll
    for (int msk = 16; msk < 64; msk <<= 1) {
        t.x += __shfl_xor(t.x, msk, 64);
        t.y += __shfl_xor(t.y, msk, 64);
        t.z += __shfl_xor(t.z, msk, 64);
        t.w += __shfl_xor(t.w, msk, 64);
    }
    if (lane < 16) {
        const float4 b = ((const float4*)bias)[lane];
        float4 o;
        o.x = t.x * 0.25f + b.x; o.y = t.y * 0.25f + b.y;
        o.z = t.z * 0.25f + b.z; o.w = t.w * 0.25f + b.w;
        ((float4*)out)[(size_t)n * 16 + lane] = o;
    }
}

__device__ __forceinline__ void softagg2_node(int n, int lane,
                                              const int* __restrict__ rowptr,
                                              const int* __restrict__ psrc,
                                              const float* __restrict__ a_s,
                                              const float* __restrict__ a_d,
                                              float* __restrict__ alpha_p,
                                              float* __restrict__ inv_s,
                                              const __half* __restrict__ xl,
                                              const float* __restrict__ bias,
                                              float* __restrict__ out) {
    const int r0 = rowptr[n], r1 = rowptr[n + 1];
    const int cl = lane & 31, half = lane >> 5, hh = cl >> 3;
    const float ad = a_d[n * NH + hh];
    const bool writer = (cl & 7) == 0;   // one lane per (half, head) writes raw w

    const h4* X = (const h4*)xl;   // row stride 32 h4 units (128 halves)
    float4 A0 = {0,0,0,0}, A1 = {0,0,0,0};
    float sum = 0.f;
    int j = r0;
    for (; j + 7 < r1; j += 8) {
        const int ja = j + half, jc = j + 2 + half, je = j + 4 + half, jg = j + 6 + half;
        const int sa = psrc[ja], sc = psrc[jc], se = psrc[je], sg = psrc[jg];
        const float wa = elw(a_s[sa * NH + hh] + ad);
        const float wc = elw(a_s[sc * NH + hh] + ad);
        const float we = elw(a_s[se * NH + hh] + ad);
        const float wg = elw(a_s[sg * NH + hh] + ad);
        if (writer) {
            alpha_p[ja * NH + hh] = wa; alpha_p[jc * NH + hh] = wc;
            alpha_p[je * NH + hh] = we; alpha_p[jg * NH + hh] = wg;
        }
        sum += (wa + wc) + (we + wg);
        const h4 va = X[(size_t)sa * 32 + cl];
        const h4 vc = X[(size_t)sc * 32 + cl];
        const h4 ve = X[(size_t)se * 32 + cl];
        const h4 vg = X[(size_t)sg * 32 + cl];
        const float2 la = __half22float2(va.a), ma = __half22float2(va.b);
        const float2 lc = __half22float2(vc.a), mc = __half22float2(vc.b);
        const float2 le = __half22float2(ve.a), me = __half22float2(ve.b);
        const float2 lg = __half22float2(vg.a), mg = __half22float2(vg.b);
        A0.x = fmaf(wa, la.x, A0.x); A0.y = fmaf(wa, la.y, A0.y);
        A0.z = fmaf(wa, ma.x, A0.z); A0.w = fmaf(wa, ma.y, A0.w);
        A1.x = fmaf(wc, lc.x, A1.x); A1.y = fmaf(wc, lc.y, A1.y);
        A1.z = fmaf(wc, mc.x, A1.z); A1.w = fmaf(wc, mc.y, A1.w);
        A0.x = fmaf(we, le.x, A0.x); A0.y = fmaf(we, le.y, A0.y);
        A0.z = fmaf(we, me.x, A0.z); A0.w = fmaf(we, me.y, A0.w);
        A1.x = fmaf(wg, lg.x, A1.x); A1.y = fmaf(wg, lg.y, A1.y);
        A1.z = fmaf(wg, mg.x, A1.z); A1.w = fmaf(wg, mg.y, A1.w);
    }
    for (; j < r1; j += 2) {
        const int ja = j + half;
        const bool valid = ja < r1;
        const int sa = psrc[valid ? ja : r0];
        float wa = 0.f;
        if (valid) {
            wa = elw(a_s[sa * NH + hh] + ad);
            if (writer) alpha_p[ja * NH + hh] = wa;
        }
        sum += wa;
        const h4 va = X[(size_t)sa * 32 + cl];
        const float2 la = __half22float2(va.a), ma = __half22float2(va.b);
        A0.x = fmaf(wa, la.x, A0.x); A0.y = fmaf(wa, la.y, A0.y);
        A0.z = fmaf(wa, ma.x, A0.z); A0.w = fmaf(wa, ma.y, A0.w);
    }
    // merge halves' partial sums, then normalize
    sum += __shfl_xor(sum, 32, 64);
    const float inv = 1.f / (sum + 1e-30f);
    if (writer && half == 0) inv_s[n * NH + hh] = inv;

    float4 t;
    t.x = A0.x + A1.x; t.y = A0.y + A1.y; t.z = A0.z + A1.z; t.w = A0.w + A1.w;
    t.x += __shfl_xor(t.x, 32, 64);
    t.y += __shfl_xor(t.y, 32, 64);
    t.z += __shfl_xor(t.z, 32, 64);
    t.w += __shfl_xor(t.w, 32, 64);
    t.x *= inv; t.y *= inv; t.z *= inv; t.w *= inv;
    #pragma unroll
    for (int q = 0; q < 2; ++q) {
        const int msk = (q == 0) ? 8 : 16;
        t.x += __shfl_xor(t.x, msk, 64);
        t.y += __shfl_xor(t.y, msk, 64);
        t.z += __shfl_xor(t.z, msk, 64);
        t.w += __shfl_xor(t.w, msk, 64);
    }
    if (lane < 8) {
        const float4 b = ((const float4*)bias)[lane];
        float4 o;
        o.x = t.x * 0.25f + b.x; o.y = t.y * 0.25f + b.y;
        o.z = t.z * 0.25f + b.z; o.w = t.w * 0.25f + b.w;
        ((float4*)out)[(size_t)n * 8 + lane] = o;
    }
}

// ================= kernels =================

// Fused independent stage: count_deg [0,EB) + pack_w1 [EB,EB+16) + layer-1 GEMM (rest).
__global__ __launch_bounds__(256) void csr_gemm1_k(const int* __restrict__ ei,
                                                   int* __restrict__ deg,
                                                   const float* __restrict__ mW1,
                                                   float* __restrict__ W1pq,
                                                   const float* __restrict__ x,
                                                   const float* __restrict__ W1,
                                                   __half* __restrict__ xlh,
                                                   const float* __restrict__ att1s,
                                                   const float* __restrict__ att1d,
                                                   float* __restrict__ a_s,
                                                   float* __restrict__ a_d) {
    __shared__ float As[16][132];
    __shared__ float Bs[16][132];
    const int b = blockIdx.x;
    if (b < EB) {
        const int e = b * 256 + threadIdx.x;
        if (e < EE) atomicAdd(&deg[ei[EE + e]], 1);
    } else if (b < EB + 16) {
        const int idx = (b - EB) * 256 + threadIdx.x;   // 32*128 = 4096 elems
        if (idx < 32 * 128) {
            const int k = idx >> 7, jj = idx & 127;
            W1pq[idx] = (jj < 64) ? mW1[k * 64 + jj] : mW1[(36 + k) * 64 + (jj - 64)];
        }
    } else {
        const int t = b - EB - 16;                      // [0, GR128*2)
        gemm_att_tile8<64, true>(x, W1, xlh, att1s, att1d, a_s, a_d,
                                 NN, INF, NH * 64,
                                 (t % GR128) * 128, (t / GR128) * 128,
                                 threadIdx.x, As, Bs);
    }
}

template <int CH, bool HOUT>
__global__ __launch_bounds__(256) void gemm_att8_k(const float* __restrict__ A,
                                                   const float* __restrict__ B,
                                                   void* __restrict__ Cv,
                                                   const float* __restrict__ att_s,
                                                   const float* __restrict__ att_d,
                                                   float* __restrict__ a_s,
                                                   float* __restrict__ a_d,
                                                   int N, int K, int M) {
    __shared__ float As[16][132];
    __shared__ float Bs[16][132];
    gemm_att_tile8<CH, HOUT>(A, B, Cv, att_s, att_d, a_s, a_d, N, K, M,
                             blockIdx.x * 128, blockIdx.y * 128, threadIdx.x, As, Bs);
}

__global__ __launch_bounds__(256) void gemm_pq8_k(const float* __restrict__ A,
                                                  const float* __restrict__ B,
                                                  __half* __restrict__ C,
                                                  int N, int K, int M) {
    __shared__ float As[16][132];
    __shared__ float Bs[16][132];
    gemm_pq_tile8(A, B, C, N, K, M, blockIdx.x * 128, blockIdx.y * 128, threadIdx.x, As, Bs);
}

// ---- multi-block exclusive scan (3 phases; logic HW-verified in R5's passing run) ----
__global__ __launch_bounds__(256) void scan1_k(const int* __restrict__ deg,
                                               int* __restrict__ bsum) {
    __shared__ int sw[4];
    const int tid = threadIdx.x, lane = tid & 63, wv = tid >> 6;
    const int i = blockIdx.x * 256 + tid;
    int s = (i < NN) ? deg[i] : 0;
    #pragma unroll
    for (int d = 1; d < 64; d <<= 1) s += __shfl_xor(s, d, 64);
    if (lane == 0) sw[wv] = s;
    __syncthreads();
    if (tid == 0) bsum[blockIdx.x] = sw[0] + sw[1] + sw[2] + sw[3];
}

__global__ __launch_bounds__(256) void scan2_k(const int* __restrict__ bsum,
                                               int* __restrict__ boff) {
    __shared__ int sw[8];
    const int tid = threadIdx.x, lane = tid & 63, wv = tid >> 6;
    int v = (tid < NCH) ? bsum[tid] : 0;
    int incl = v;
    #pragma unroll
    for (int d = 1; d < 64; d <<= 1) {
        int t = __shfl_up(incl, d, 64);
        if (lane >= d) incl += t;
    }
    if (lane == 63) sw[wv] = incl;
    __syncthreads();
    if (wv == 0 && lane < 4) {
        int s4 = sw[lane];
        #pragma unroll
        for (int d = 1; d < 4; d <<= 1) {
            int t = __shfl_up(s4, d, 64);
            if (lane >= d) s4 += t;
        }
        sw[lane + 4] = s4;
    }
    __syncthreads();
    const int woff = (wv > 0) ? sw[wv - 1 + 4] : 0;
    if (tid < NCH) boff[tid] = woff + incl - v;
}

__global__ __launch_bounds__(256) void scan3_k(const int* __restrict__ deg,
                                               const int* __restrict__ boff,
                                               int* __restrict__ rowptr,
                                               int* __restrict__ cursor) {
    __shared__ int sw[8];
    const int tid = threadIdx.x, lane = tid & 63, wv = tid >> 6;
    const int c = blockIdx.x;
    const int i = c * 256 + tid;
    int v = (i < NN) ? deg[i] : 0;
    int incl = v;
    #pragma unroll
    for (int d = 1; d < 64; d <<= 1) {
        int t = __shfl_up(incl, d, 64);
        if (lane >= d) incl += t;
    }
    if (lane == 63) sw[wv] = incl;
    __syncthreads();
    if (wv == 0 && lane < 4) {
        int s4 = sw[lane];
        #pragma unroll
        for (int d = 1; d < 4; d <<= 1) {
            int t = __shfl_up(s4, d, 64);
            if (lane >= d) s4 += t;
        }
        sw[lane + 4] = s4;
    }
    __syncthreads();
    const int excl = boff[c] + ((wv > 0) ? sw[wv - 1 + 4] : 0) + incl - v;
    if (i < NN) { rowptr[i] = excl; cursor[i] = excl; }
    if (c == 0 && tid == 0) rowptr[NN] = EE;
}

__global__ __launch_bounds__(256) void scatter_perm_k(const int* __restrict__ ei,
                                                      int* __restrict__ cursor,
                                                      int* __restrict__ perm,
                                                      int* __restrict__ psrc,
                                                      int* __restrict__ pdst) {
    const int e = blockIdx.x * 256 + threadIdx.x;
    if (e >= EE) return;
    const int d = ei[EE + e];
    const int p = atomicAdd(&cursor[d], 1);
    perm[p] = e;
    psrc[p] = ei[e];
    pdst[p] = d;
}

__global__ __launch_bounds__(256) void softagg1h_k(const int* __restrict__ rowptr,
                                                   const int* __restrict__ psrc,
                                                   const float* __restrict__ a_s,
                                                   const float* __restrict__ a_d,
                                                   const __half* __restrict__ xl,
                                                   const float* __restrict__ bias,
                                                   float* __restrict__ out) {
    const int n = blockIdx.x * 4 + (threadIdx.x >> 6);
    if (n >= NN) return;
    softagg1_node(n, threadIdx.x & 63, rowptr, psrc, a_s, a_d, xl, bias, out);
}

__global__ __launch_bounds__(256) void softagg2h_k(const int* __restrict__ rowptr,
                                                   const int* __restrict__ psrc,
                                                   const float* __restrict__ a_s,
                                                   const float* __restrict__ a_d,
                                                   float* __restrict__ alpha_p,
                                                   float* __restrict__ inv_s,
                                                   const __half* __restrict__ xl,
                                                   const float* __restrict__ bias,
                                                   float* __restrict__ out) {
    const int n = blockIdx.x * 4 + (threadIdx.x >> 6);
    if (n >= NN) return;
    softagg2_node(n, threadIdx.x & 63, rowptr, psrc, a_s, a_d, alpha_p, inv_s, xl, bias, out);
}

__global__ __launch_bounds__(256) void edge_mlp_k(const __half* __restrict__ PQ,
                                                  const float* __restrict__ alpha_p,
                                                  const float* __restrict__ inv_s,
                                                  const int* __restrict__ psrc,
                                                  const int* __restrict__ pdst,
                                                  const int* __restrict__ perm,
                                                  const float* __restrict__ mW1,
                                                  const float* __restrict__ mb1,
                                                  const float* __restrict__ mW2,
                                                  const float* __restrict__ mb2,
                                                  float* __restrict__ out) {
    const int lane = threadIdx.x & 63, wvv = threadIdx.x >> 6;
    const int g = lane >> 4, c = lane & 15;

    const float4 wa0 = *(const float4*)&mW1[32 * 64 + c * 4];
    const float4 wa1 = *(const float4*)&mW1[33 * 64 + c * 4];
    const float4 wa2 = *(const float4*)&mW1[34 * 64 + c * 4];
    const float4 wa3 = *(const float4*)&mW1[35 * 64 + c * 4];
    const float4 b1v = *(const float4*)&mb1[c * 4];
    const float4 w2a = *(const float4*)&mW2[c * 8];
    const float4 w2b = *(const float4*)&mW2[c * 8 + 4];
    const float bo0 = mb2[0], bo1 = mb2[1];

    const h4* PQ4 = (const h4*)PQ;
    const int gw = blockIdx.x * 4 + wvv;
    const int stride4 = gridDim.x * 4 * 4;

    for (int jb = gw * 4; jb < EE; jb += stride4) {
        const int j = jb + g;
        const int s = psrc[j];
        const int d = pdst[j];
        const float4 ar = *(const float4*)&alpha_p[(size_t)j * 4];
        const float4 iv = *(const float4*)&inv_s[(size_t)d * 4];
        const float al0 = ar.x * iv.x, al1 = ar.y * iv.y;
        const float al2 = ar.z * iv.z, al3 = ar.w * iv.w;
        const h4 ph = PQ4[(size_t)s * 32 + c];
        const h4 qh = PQ4[(size_t)d * 32 + 16 + c];
        const float2 pl = __half22float2(ph.a), pm = __half22float2(ph.b);
        const float2 ql = __half22float2(qh.a), qm = __half22float2(qh.b);
        float4 h;
        h.x = pl.x + ql.x + b1v.x; h.y = pl.y + ql.y + b1v.y;
        h.z = pm.x + qm.x + b1v.z; h.w = pm.y + qm.y + b1v.w;
        h.x = fmaf(al0, wa0.x, h.x); h.y = fmaf(al0, wa0.y, h.y);
        h.z = fmaf(al0, wa0.z, h.z); h.w = fmaf(al0, wa0.w, h.w);
        h.x = fmaf(al1, wa1.x, h.x); h.y = fmaf(al1, wa1.y, h.y);
        h.z = fmaf(al1, wa1.z, h.z); h.w = fmaf(al1, wa1.w, h.w);
        h.x = fmaf(al2, wa2.x, h.x); h.y = fmaf(al2, wa2.y, h.y);
        h.z = fmaf(al2, wa2.z, h.z); h.w = fmaf(al2, wa2.w, h.w);
        h.x = fmaf(al3, wa3.x, h.x); h.y = fmaf(al3, wa3.y, h.y);
        h.z = fmaf(al3, wa3.z, h.z); h.w = fmaf(al3, wa3.w, h.w);
        h.x = fmaxf(h.x, 0.f); h.y = fmaxf(h.y, 0.f);
        h.z = fmaxf(h.z, 0.f); h.w = fmaxf(h.w, 0.f);

        float v0 = h.x * w2a.x + h.y * w2a.z + h.z * w2b.x + h.w * w2b.z;
        float v1 = h.x * w2a.y + h.y * w2a.w + h.z * w2b.y + h.w * w2b.w;
        #pragma unroll
        for (int msk = 1; msk < 16; msk <<= 1) {
            v0 += __shfl_xor(v0, msk, 64);
            v1 += __shfl_xor(v1, msk, 64);
        }
        if (c == 0)
            *(float2*)&out[(size_t)perm[j] * 2] = make_float2(v0 + bo0, v1 + bo1);
    }
}

extern "C" void kernel_launch(void* const* d_in, const int* in_sizes, int n_in,
                              void* d_out, int out_size, void* d_ws, size_t ws_size,
                              hipStream_t stream) {
    const float* x        = (const float*)d_in[0];
    const int*   ei       = (const int*)d_in[1];
    // d_in[2] edge_attr: unused (edge_dim=None). d_in[3] flag: unused.
    const float* W1       = (const float*)d_in[4];
    const float* att1_src = (const float*)d_in[5];
    const float* att1_dst = (const float*)d_in[6];
    const float* b1       = (const float*)d_in[7];
    const float* W3       = (const float*)d_in[8];
    const float* att3_src = (const float*)d_in[9];
    const float* att3_dst = (const float*)d_in[10];
    const float* b3       = (const float*)d_in[11];
    const float* mW1      = (const float*)d_in[12];
    const float* mb1      = (const float*)d_in[13];
    const float* mW2      = (const float*)d_in[14];
    const float* mb2      = (const float*)d_in[15];

    float* out_nodes = (float*)d_out;               // [N,32]
    float* out_edges = out_nodes + (size_t)NN * 32; // [E,2]

    // workspace layout (floats/ints)
    float* ws = (float*)d_ws;
    __half*   xlh     = (__half*)ws;                  // N*256 halves (layer-1 GEMM out)
    __half*   xl2h    = (__half*)ws;                  // N*128 halves (layer-2 GEMM out)
    __half*   PQh     = (__half*)ws;                  // N*128 halves, after xl2h dead
    float*    h1      = ws + 12800000;                // N*64
    float*    alpha_p = ws + 16000000;                // E*4 (CSR-order raw w, layer 2)
    float*    a_s     = ws + 25600000;                // N*4
    float*    a_d     = ws + 25800000;                // N*4
    float*    W1pq    = ws + 26000000;                // 32*128
    float*    inv_s   = ws + 26100000;                // N*4
    int*      bsum    = (int*)(ws + 26300000);        // NCH
    int*      boff    = (int*)(ws + 26301000);        // NCH
    int*      deg     = (int*)(ws + 26400000);        // N
    int*      cursor  = (int*)(ws + 26450000);        // N
    int*      rowptr  = (int*)(ws + 26500000);        // N+1
    int*      perm    = (int*)(ws + 26550008);        // E
    int*      psrc    = (int*)(ws + 27350008);        // E
    int*      pdst    = (int*)(ws + 28150008);        // E

    const int NB4 = (NN + 3) / 4;

    // 1) zero deg
    hipMemsetAsync(deg, 0, (size_t)NN * 4, stream);
    // 2) fused: count_deg + pack_w1 + layer-1 GEMM (128-tile) — mutually independent
    csr_gemm1_k<<<EB + 16 + GR128 * 2, 256, 0, stream>>>(ei, deg, mW1, W1pq,
                                                         x, W1, xlh,
                                                         att1_src, att1_dst, a_s, a_d);
    // 3) multi-block exclusive scan -> rowptr/cursor
    scan1_k<<<NCH, 256, 0, stream>>>(deg, bsum);
    scan2_k<<<1, 256, 0, stream>>>(bsum, boff);
    scan3_k<<<NCH, 256, 0, stream>>>(deg, boff, rowptr, cursor);
    // 4) scatter edges into CSR order
    scatter_perm_k<<<EB, 256, 0, stream>>>(ei, cursor, perm, psrc, pdst);
    // 5) layer-1 softmax+aggregate
    softagg1h_k<<<NB4, 256, 0, stream>>>(rowptr, psrc, a_s, a_d, xlh, b1, h1);
    // 6) layer-2 GEMM (128-tile; M=128 -> one col tile)
    gemm_att8_k<32, true><<<dim3(GR128, 1), 256, 0, stream>>>(h1, W3, xl2h,
                                                              att3_src, att3_dst,
                                                              a_s, a_d, NN, 64, NH * 32);
    // 7) layer-2 softmax+aggregate
    softagg2h_k<<<NB4, 256, 0, stream>>>(rowptr, psrc, a_s, a_d, alpha_p, inv_s, xl2h, b3,
                                         out_nodes);
    // 8) PQ GEMM (xl2h dead -> PQh aliases it)
    gemm_pq8_k<<<dim3(GR128, 1), 256, 0, stream>>>(out_nodes, W1pq, PQh, NN, 32, 128);
    // 9) edge MLP
    edge_mlp_k<<<2048, 256, 0, stream>>>(PQh, alpha_p, inv_s, psrc, pdst, perm,
                                         mW1, mb1, mW2, mb2, out_edges);
}

// Round 8
// 447.634 us; speedup vs baseline: 2.7239x; 1.0099x over previous
//
#include <hip/hip_runtime.h>
#include <hip/hip_fp16.h>

// Problem constants
constexpr int NN   = 50000;
constexpr int EE   = 800000;
constexpr int INF  = 128;   // input feat
constexpr int NH   = 4;     // heads
constexpr int GR64 = (NN + 63) / 64;        // 782 row tiles (64-row GEMM tiling)
constexpr int EB   = (EE + 255) / 256;      // 3125 edge blocks
constexpr int NCH  = (NN + 255) / 256;      // 196 scan chunks

struct __align__(8) h4 { __half2 a, b; };   // 4 halves = 8 bytes

__device__ __forceinline__ float elw(float a) {
    a = (a > 0.f) ? a : 0.2f * a;          // leaky_relu(0.2)
    return __expf(a);                       // exp without max-sub (scores bounded)
}

// ======== 64x128 tile fp32 GEMM, 4 rows x (4+4 split) cols per thread ========
// Per kk: 32 FMA (64 cyc) / 3 ds_read_b128 (~38 cyc) -> ~64% VALU ceiling.
// Split-col reads (stride 16B) = 2-way bank conflict = free (vs 8-wide 4-way).
// 1564 blocks for layer-1 -> ~6 blocks/CU (occupancy preserved).

template <int CH, bool HOUT>
__device__ __forceinline__ void gemm_att_tile48(const float* __restrict__ A,
                                                const float* __restrict__ B,
                                                void* __restrict__ Cv,
                                                const float* __restrict__ att_s,
                                                const float* __restrict__ att_d,
                                                float* __restrict__ a_s,
                                                float* __restrict__ a_d,
                                                int N, int K, int M,
                                                int row0, int col0, int tid,
                                                float (*As)[68], float (*Bs)[132]) {
    const int tx = tid & 15, ty = tid >> 4;
    float acc[4][8] = {};   // [row][col]: cols 0-3 = group0 (col0+tx*4), 4-7 = group1 (+64)

    for (int k0 = 0; k0 < K; k0 += 16) {
        {
            const int a_row = tid >> 2;          // 0..63
            const int a_k   = (tid & 3) * 4;
            const int gr    = row0 + a_row;
            float4 v = make_float4(0.f, 0.f, 0.f, 0.f);
            if (gr < N) v = *(const float4*)(A + (size_t)gr * K + k0 + a_k);
            As[a_k + 0][a_row] = v.x;
            As[a_k + 1][a_row] = v.y;
            As[a_k + 2][a_row] = v.z;
            As[a_k + 3][a_row] = v.w;
        }
        {
            const int b_k = tid >> 4;            // 0..15
            const int b_c = (tid & 15) * 8;
            const float* bp = B + (size_t)(k0 + b_k) * M + col0 + b_c;
            *(float4*)&Bs[b_k][b_c]     = *(const float4*)bp;
            *(float4*)&Bs[b_k][b_c + 4] = *(const float4*)(bp + 4);
        }
        __syncthreads();
        #pragma unroll
        for (int kk = 0; kk < 16; ++kk) {
            const float4 a  = *(const float4*)&As[kk][ty * 4];
            const float4 b0 = *(const float4*)&Bs[kk][tx * 4];        // group0
            const float4 b1 = *(const float4*)&Bs[kk][64 + tx * 4];   // group1
            const float av[4] = {a.x, a.y, a.z, a.w};
            const float bv[8] = {b0.x,b0.y,b0.z,b0.w,b1.x,b1.y,b1.z,b1.w};
            #pragma unroll
            for (int i = 0; i < 4; ++i)
                #pragma unroll
                for (int j = 0; j < 8; ++j)
                    acc[i][j] = fmaf(av[i], bv[j], acc[i][j]);
        }
        __syncthreads();
    }

    // epilogue: each thread holds 4 cols of TWO heads' column groups
    const int c0 = col0 + tx * 4;        // group0 cols
    const int c1 = c0 + 64;              // group1 cols
    const int head0 = c0 / CH, pos0 = c0 % CH;
    const int head1 = c1 / CH, pos1 = c1 % CH;
    float attS[8], attD[8];
    #pragma unroll
    for (int j = 0; j < 4; ++j) {
        attS[j]     = att_s[head0 * CH + pos0 + j];
        attD[j]     = att_d[head0 * CH + pos0 + j];
        attS[j + 4] = att_s[head1 * CH + pos1 + j];
        attD[j + 4] = att_d[head1 * CH + pos1 + j];
    }
    #pragma unroll
    for (int i = 0; i < 4; ++i) {
        const int r = row0 + ty * 4 + i;
        if (r < N) {
            if constexpr (HOUT) {
                __half* C = (__half*)Cv;
                __half* cp0 = C + (size_t)r * M + c0;
                __half* cp1 = C + (size_t)r * M + c1;
                *(__half2*)(cp0)     = __halves2half2(__float2half_rn(acc[i][0]), __float2half_rn(acc[i][1]));
                *(__half2*)(cp0 + 2) = __halves2half2(__float2half_rn(acc[i][2]), __float2half_rn(acc[i][3]));
                *(__half2*)(cp1)     = __halves2half2(__float2half_rn(acc[i][4]), __float2half_rn(acc[i][5]));
                *(__half2*)(cp1 + 2) = __halves2half2(__float2half_rn(acc[i][6]), __float2half_rn(acc[i][7]));
            } else {
                float* C = (float*)Cv;
                *(float4*)(C + (size_t)r * M + c0) = make_float4(acc[i][0], acc[i][1], acc[i][2], acc[i][3]);
                *(float4*)(C + (size_t)r * M + c1) = make_float4(acc[i][4], acc[i][5], acc[i][6], acc[i][7]);
            }
        }
        float ss0 = 0.f, sd0 = 0.f, ss1 = 0.f, sd1 = 0.f;
        #pragma unroll
        for (int j = 0; j < 4; ++j) {
            ss0 = fmaf(acc[i][j], attS[j], ss0);
            sd0 = fmaf(acc[i][j], attD[j], sd0);
            ss1 = fmaf(acc[i][j + 4], attS[j + 4], ss1);
            sd1 = fmaf(acc[i][j + 4], attD[j + 4], sd1);
        }
        #pragma unroll
        for (int msk = 1; msk < CH / 4; msk <<= 1) {
            ss0 += __shfl_xor(ss0, msk, 64);
            sd0 += __shfl_xor(sd0, msk, 64);
            ss1 += __shfl_xor(ss1, msk, 64);
            sd1 += __shfl_xor(sd1, msk, 64);
        }
        if ((tx & (CH / 4 - 1)) == 0 && r < N) {
            a_s[r * NH + head0] = ss0;
            a_d[r * NH + head0] = sd0;
            a_s[r * NH + head1] = ss1;
            a_d[r * NH + head1] = sd1;
        }
    }
}

__device__ __forceinline__ void gemm_pq_tile48(const float* __restrict__ A,
                                               const float* __restrict__ B,
                                               __half* __restrict__ C,
                                               int N, int K, int M,
                                               int row0, int col0, int tid,
                                               float (*As)[68], float (*Bs)[132]) {
    const int tx = tid & 15, ty = tid >> 4;
    float acc[4][8] = {};
    for (int k0 = 0; k0 < K; k0 += 16) {
        {
            const int a_row = tid >> 2;
            const int a_k   = (tid & 3) * 4;
            const int gr    = row0 + a_row;
            float4 v = make_float4(0.f, 0.f, 0.f, 0.f);
            if (gr < N) v = *(const float4*)(A + (size_t)gr * K + k0 + a_k);
            As[a_k + 0][a_row] = v.x;
            As[a_k + 1][a_row] = v.y;
            As[a_k + 2][a_row] = v.z;
            As[a_k + 3][a_row] = v.w;
        }
        {
            const int b_k = tid >> 4;
            const int b_c = (tid & 15) * 8;
            const float* bp = B + (size_t)(k0 + b_k) * M + col0 + b_c;
            *(float4*)&Bs[b_k][b_c]     = *(const float4*)bp;
            *(float4*)&Bs[b_k][b_c + 4] = *(const float4*)(bp + 4);
        }
        __syncthreads();
        #pragma unroll
        for (int kk = 0; kk < 16; ++kk) {
            const float4 a  = *(const float4*)&As[kk][ty * 4];
            const float4 b0 = *(const float4*)&Bs[kk][tx * 4];
            const float4 b1 = *(const float4*)&Bs[kk][64 + tx * 4];
            const float av[4] = {a.x, a.y, a.z, a.w};
            const float bv[8] = {b0.x,b0.y,b0.z,b0.w,b1.x,b1.y,b1.z,b1.w};
            #pragma unroll
            for (int i = 0; i < 4; ++i)
                #pragma unroll
                for (int j = 0; j < 8; ++j)
                    acc[i][j] = fmaf(av[i], bv[j], acc[i][j]);
        }
        __syncthreads();
    }
    const int c0 = col0 + tx * 4;
    const int c1 = c0 + 64;
    #pragma unroll
    for (int i = 0; i < 4; ++i) {
        const int r = row0 + ty * 4 + i;
        if (r < N) {
            __half* cp0 = C + (size_t)r * M + c0;
            __half* cp1 = C + (size_t)r * M + c1;
            *(__half2*)(cp0)     = __halves2half2(__float2half_rn(acc[i][0]), __float2half_rn(acc[i][1]));
            *(__half2*)(cp0 + 2) = __halves2half2(__float2half_rn(acc[i][2]), __float2half_rn(acc[i][3]));
            *(__half2*)(cp1)     = __halves2half2(__float2half_rn(acc[i][4]), __float2half_rn(acc[i][5]));
            *(__half2*)(cp1 + 2) = __halves2half2(__float2half_rn(acc[i][6]), __float2half_rn(acc[i][7]));
        }
    }
}

// ================= softmax+aggregate device helpers (proven R4 bodies) =================

__device__ __forceinline__ void softagg1_node(int n, int lane,
                                              const int* __restrict__ rowptr,
                                              const int* __restrict__ psrc,
                                              const float* __restrict__ a_s,
                                              const float* __restrict__ a_d,
                                              const __half* __restrict__ xl,
                                              const float* __restrict__ bias,
                                              float* __restrict__ out) {
    const int r0 = rowptr[n], r1 = rowptr[n + 1];
    const int hh = lane >> 4;
    const float ad = a_d[n * NH + hh];

    const h4* X = (const h4*)xl;   // row stride 64 h4 units (256 halves)
    float4 A0 = {0,0,0,0}, A1 = {0,0,0,0}, A2 = {0,0,0,0}, A3 = {0,0,0,0};
    float sum = 0.f;
    int j = r0;
    for (; j + 7 < r1; j += 8) {
        const int s0 = psrc[j],     s1 = psrc[j + 1], s2 = psrc[j + 2], s3 = psrc[j + 3];
        const int s4 = psrc[j + 4], s5 = psrc[j + 5], s6 = psrc[j + 6], s7 = psrc[j + 7];
        const float w0 = elw(a_s[s0 * NH + hh] + ad);
        const float w1 = elw(a_s[s1 * NH + hh] + ad);
        const float w2 = elw(a_s[s2 * NH + hh] + ad);
        const float w3 = elw(a_s[s3 * NH + hh] + ad);
        const float w4 = elw(a_s[s4 * NH + hh] + ad);
        const float w5 = elw(a_s[s5 * NH + hh] + ad);
        const float w6 = elw(a_s[s6 * NH + hh] + ad);
        const float w7 = elw(a_s[s7 * NH + hh] + ad);
        sum += ((w0 + w1) + (w2 + w3)) + ((w4 + w5) + (w6 + w7));
        const h4 v0 = X[(size_t)s0 * 64 + lane];
        const h4 v1 = X[(size_t)s1 * 64 + lane];
        const h4 v2 = X[(size_t)s2 * 64 + lane];
        const h4 v3 = X[(size_t)s3 * 64 + lane];
        const h4 v4 = X[(size_t)s4 * 64 + lane];
        const h4 v5 = X[(size_t)s5 * 64 + lane];
        const h4 v6 = X[(size_t)s6 * 64 + lane];
        const h4 v7 = X[(size_t)s7 * 64 + lane];
        float2 l0 = __half22float2(v0.a), m0 = __half22float2(v0.b);
        float2 l1 = __half22float2(v1.a), m1 = __half22float2(v1.b);
        float2 l2 = __half22float2(v2.a), m2 = __half22float2(v2.b);
        float2 l3 = __half22float2(v3.a), m3 = __half22float2(v3.b);
        float2 l4 = __half22float2(v4.a), m4 = __half22float2(v4.b);
        float2 l5 = __half22float2(v5.a), m5 = __half22float2(v5.b);
        float2 l6 = __half22float2(v6.a), m6 = __half22float2(v6.b);
        float2 l7 = __half22float2(v7.a), m7 = __half22float2(v7.b);
        A0.x = fmaf(w0, l0.x, A0.x); A0.y = fmaf(w0, l0.y, A0.y);
        A0.z = fmaf(w0, m0.x, A0.z); A0.w = fmaf(w0, m0.y, A0.w);
        A1.x = fmaf(w1, l1.x, A1.x); A1.y = fmaf(w1, l1.y, A1.y);
        A1.z = fmaf(w1, m1.x, A1.z); A1.w = fmaf(w1, m1.y, A1.w);
        A2.x = fmaf(w2, l2.x, A2.x); A2.y = fmaf(w2, l2.y, A2.y);
        A2.z = fmaf(w2, m2.x, A2.z); A2.w = fmaf(w2, m2.y, A2.w);
        A3.x = fmaf(w3, l3.x, A3.x); A3.y = fmaf(w3, l3.y, A3.y);
        A3.z = fmaf(w3, m3.x, A3.z); A3.w = fmaf(w3, m3.y, A3.w);
        A0.x = fmaf(w4, l4.x, A0.x); A0.y = fmaf(w4, l4.y, A0.y);
        A0.z = fmaf(w4, m4.x, A0.z); A0.w = fmaf(w4, m4.y, A0.w);
        A1.x = fmaf(w5, l5.x, A1.x); A1.y = fmaf(w5, l5.y, A1.y);
        A1.z = fmaf(w5, m5.x, A1.z); A1.w = fmaf(w5, m5.y, A1.w);
        A2.x = fmaf(w6, l6.x, A2.x); A2.y = fmaf(w6, l6.y, A2.y);
        A2.z = fmaf(w6, m6.x, A2.z); A2.w = fmaf(w6, m6.y, A2.w);
        A3.x = fmaf(w7, l7.x, A3.x); A3.y = fmaf(w7, l7.y, A3.y);
        A3.z = fmaf(w7, m7.x, A3.z); A3.w = fmaf(w7, m7.y, A3.w);
    }
    for (; j < r1; ++j) {
        const int s0 = psrc[j];
        const float w0 = elw(a_s[s0 * NH + hh] + ad);
        sum += w0;
        const h4 v0 = X[(size_t)s0 * 64 + lane];
        float2 l0 = __half22float2(v0.a), m0 = __half22float2(v0.b);
        A0.x = fmaf(w0, l0.x, A0.x); A0.y = fmaf(w0, l0.y, A0.y);
        A0.z = fmaf(w0, m0.x, A0.z); A0.w = fmaf(w0, m0.y, A0.w);
    }
    const float inv = 1.f / (sum + 1e-30f);
    float4 t;
    t.x = ((A0.x + A1.x) + (A2.x + A3.x)) * inv;
    t.y = ((A0.y + A1.y) + (A2.y + A3.y)) * inv;
    t.z = ((A0.z + A1.z) + (A2.z + A3.z)) * inv;
    t.w = ((A0.w + A1.w) + (A2.w + A3.w)) * inv;
    #pragma unroll
    for (int msk = 16; msk < 64; msk <<= 1) {
        t.x += __shfl_xor(t.x, msk, 64);
        t.y += __shfl_xor(t.y, msk, 64);
        t.z += __shfl_xor(t.z, msk, 64);
        t.w += __shfl_xor(t.w, msk, 64);
    }
    if (lane < 16) {
        const float4 b = ((const float4*)bias)[lane];
        float4 o;
        o.x = t.x * 0.25f + b.x; o.y = t.y * 0.25f + b.y;
        o.z = t.z * 0.25f + b.z; o.w = t.w * 0.25f + b.w;
        ((float4*)out)[(size_t)n * 16 + lane] = o;
    }
}

__device__ __forceinline__ void softagg2_node(int n, int lane,
                                              const int* __restrict__ rowptr,
                                              const int* __restrict__ psrc,
                                              const float* __restrict__ a_s,
                                              const float* __restrict__ a_d,
                                              float* __restrict__ alpha_p,
                                              float* __restrict__ inv_s,
                                              const __half* __restrict__ xl,
                                              const float* __restrict__ bias,
                                              float* __restrict__ out) {
    const int r0 = rowptr[n], r1 = rowptr[n + 1];
    const int cl = lane & 31, half = lane >> 5, hh = cl >> 3;
    const float ad = a_d[n * NH + hh];
    const bool writer = (cl & 7) == 0;   // one lane per (half, head) writes raw w

    const h4* X = (const h4*)xl;   // row stride 32 h4 units (128 halves)
    float4 A0 = {0,0,0,0}, A1 = {0,0,0,0};
    float sum = 0.f;
    int j = r0;
    for (; j + 7 < r1; j += 8) {
        const int ja = j + half, jc = j + 2 + half, je = j + 4 + half, jg = j + 6 + half;
        const int sa = psrc[ja], sc = psrc[jc], se = psrc[je], sg = psrc[jg];
        const float wa = elw(a_s[sa * NH + hh] + ad);
        const float wc = elw(a_s[sc * NH + hh] + ad);
        const float we = elw(a_s[se * NH + hh] + ad);
        const float wg = elw(a_s[sg * NH + hh] + ad);
        if (writer) {
            alpha_p[ja * NH + hh] = wa; alpha_p[jc * NH + hh] = wc;
            alpha_p[je * NH + hh] = we; alpha_p[jg * NH + hh] = wg;
        }
        sum += (wa + wc) + (we + wg);
        const h4 va = X[(size_t)sa * 32 + cl];
        const h4 vc = X[(size_t)sc * 32 + cl];
        const h4 ve = X[(size_t)se * 32 + cl];
        const h4 vg = X[(size_t)sg * 32 + cl];
        const float2 la = __half22float2(va.a), ma = __half22float2(va.b);
        const float2 lc = __half22float2(vc.a), mc = __half22float2(vc.b);
        const float2 le = __half22float2(ve.a), me = __half22float2(ve.b);
        const float2 lg = __half22float2(vg.a), mg = __half22float2(vg.b);
        A0.x = fmaf(wa, la.x, A0.x); A0.y = fmaf(wa, la.y, A0.y);
        A0.z = fmaf(wa, ma.x, A0.z); A0.w = fmaf(wa, ma.y, A0.w);
        A1.x = fmaf(wc, lc.x, A1.x); A1.y = fmaf(wc, lc.y, A1.y);
        A1.z = fmaf(wc, mc.x, A1.z); A1.w = fmaf(wc, mc.y, A1.w);
        A0.x = fmaf(we, le.x, A0.x); A0.y = fmaf(we, le.y, A0.y);
        A0.z = fmaf(we, me.x, A0.z); A0.w = fmaf(we, me.y, A0.w);
        A1.x = fmaf(wg, lg.x, A1.x); A1.y = fmaf(wg, lg.y, A1.y);
        A1.z = fmaf(wg, mg.x, A1.z); A1.w = fmaf(wg, mg.y, A1.w);
    }
    for (; j < r1; j += 2) {
        const int ja = j + half;
        const bool valid = ja < r1;
        const int sa = psrc[valid ? ja : r0];
        float wa = 0.f;
        if (valid) {
            wa = elw(a_s[sa * NH + hh] + ad);
            if (writer) alpha_p[ja * NH + hh] = wa;
        }
        sum += wa;
        const h4 va = X[(size_t)sa * 32 + cl];
        const float2 la = __half22float2(va.a), ma = __half22float2(va.b);
        A0.x = fmaf(wa, la.x, A0.x); A0.y = fmaf(wa, la.y, A0.y);
        A0.z = fmaf(wa, ma.x, A0.z); A0.w = fmaf(wa, ma.y, A0.w);
    }
    // merge halves' partial sums, then normalize
    sum += __shfl_xor(sum, 32, 64);
    const float inv = 1.f / (sum + 1e-30f);
    if (writer && half == 0) inv_s[n * NH + hh] = inv;

    float4 t;
    t.x = A0.x + A1.x; t.y = A0.y + A1.y; t.z = A0.z + A1.z; t.w = A0.w + A1.w;
    t.x += __shfl_xor(t.x, 32, 64);
    t.y += __shfl_xor(t.y, 32, 64);
    t.z += __shfl_xor(t.z, 32, 64);
    t.w += __shfl_xor(t.w, 32, 64);
    t.x *= inv; t.y *= inv; t.z *= inv; t.w *= inv;
    #pragma unroll
    for (int q = 0; q < 2; ++q) {
        const int msk = (q == 0) ? 8 : 16;
        t.x += __shfl_xor(t.x, msk, 64);
        t.y += __shfl_xor(t.y, msk, 64);
        t.z += __shfl_xor(t.z, msk, 64);
        t.w += __shfl_xor(t.w, msk, 64);
    }
    if (lane < 8) {
        const float4 b = ((const float4*)bias)[lane];
        float4 o;
        o.x = t.x * 0.25f + b.x; o.y = t.y * 0.25f + b.y;
        o.z = t.z * 0.25f + b.z; o.w = t.w * 0.25f + b.w;
        ((float4*)out)[(size_t)n * 8 + lane] = o;
    }
}

// ================= kernels =================

// Fused independent stage: count_deg [0,EB) + pack_w1 [EB,EB+16) + layer-1 GEMM (rest).
__global__ __launch_bounds__(256) void csr_gemm1_k(const int* __restrict__ ei,
                                                   int* __restrict__ deg,
                                                   const float* __restrict__ mW1,
                                                   float* __restrict__ W1pq,
                                                   const float* __restrict__ x,
                                                   const float* __restrict__ W1,
                                                   __half* __restrict__ xlh,
                                                   const float* __restrict__ att1s,
                                                   const float* __restrict__ att1d,
                                                   float* __restrict__ a_s,
                                                   float* __restrict__ a_d) {
    __shared__ float As[16][68];
    __shared__ float Bs[16][132];
    const int b = blockIdx.x;
    if (b < EB) {
        const int e = b * 256 + threadIdx.x;
        if (e < EE) atomicAdd(&deg[ei[EE + e]], 1);
    } else if (b < EB + 16) {
        const int idx = (b - EB) * 256 + threadIdx.x;   // 32*128 = 4096 elems
        if (idx < 32 * 128) {
            const int k = idx >> 7, jj = idx & 127;
            W1pq[idx] = (jj < 64) ? mW1[k * 64 + jj] : mW1[(36 + k) * 64 + (jj - 64)];
        }
    } else {
        const int t = b - EB - 16;                      // [0, GR64*2)
        gemm_att_tile48<64, true>(x, W1, xlh, att1s, att1d, a_s, a_d,
                                  NN, INF, NH * 64,
                                  (t % GR64) * 64, (t / GR64) * 128,
                                  threadIdx.x, As, Bs);
    }
}

template <int CH, bool HOUT>
__global__ __launch_bounds__(256) void gemm_att48_k(const float* __restrict__ A,
                                                    const float* __restrict__ B,
                                                    void* __restrict__ Cv,
                                                    const float* __restrict__ att_s,
                                                    const float* __restrict__ att_d,
                                                    float* __restrict__ a_s,
                                                    float* __restrict__ a_d,
                                                    int N, int K, int M) {
    __shared__ float As[16][68];
    __shared__ float Bs[16][132];
    gemm_att_tile48<CH, HOUT>(A, B, Cv, att_s, att_d, a_s, a_d, N, K, M,
                              blockIdx.x * 64, blockIdx.y * 128, threadIdx.x, As, Bs);
}

__global__ __launch_bounds__(256) void gemm_pq48_k(const float* __restrict__ A,
                                                   const float* __restrict__ B,
                                                   __half* __restrict__ C,
                                                   int N, int K, int M) {
    __shared__ float As[16][68];
    __shared__ float Bs[16][132];
    gemm_pq_tile48(A, B, C, N, K, M, blockIdx.x * 64, blockIdx.y * 128, threadIdx.x, As, Bs);
}

// ---- multi-block exclusive scan (3 phases; HW-verified logic) ----
__global__ __launch_bounds__(256) void scan1_k(const int* __restrict__ deg,
                                               int* __restrict__ bsum) {
    __shared__ int sw[4];
    const int tid = threadIdx.x, lane = tid & 63, wv = tid >> 6;
    const int i = blockIdx.x * 256 + tid;
    int s = (i < NN) ? deg[i] : 0;
    #pragma unroll
    for (int d = 1; d < 64; d <<= 1) s += __shfl_xor(s, d, 64);
    if (lane == 0) sw[wv] = s;
    __syncthreads();
    if (tid == 0) bsum[blockIdx.x] = sw[0] + sw[1] + sw[2] + sw[3];
}

__global__ __launch_bounds__(256) void scan2_k(const int* __restrict__ bsum,
                                               int* __restrict__ boff) {
    __shared__ int sw[8];
    const int tid = threadIdx.x, lane = tid & 63, wv = tid >> 6;
    int v = (tid < NCH) ? bsum[tid] : 0;
    int incl = v;
    #pragma unroll
    for (int d = 1; d < 64; d <<= 1) {
        int t = __shfl_up(incl, d, 64);
        if (lane >= d) incl += t;
    }
    if (lane == 63) sw[wv] = incl;
    __syncthreads();
    if (wv == 0 && lane < 4) {
        int s4 = sw[lane];
        #pragma unroll
        for (int d = 1; d < 4; d <<= 1) {
            int t = __shfl_up(s4, d, 64);
            if (lane >= d) s4 += t;
        }
        sw[lane + 4] = s4;
    }
    __syncthreads();
    const int woff = (wv > 0) ? sw[wv - 1 + 4] : 0;
    if (tid < NCH) boff[tid] = woff + incl - v;
}

__global__ __launch_bounds__(256) void scan3_k(const int* __restrict__ deg,
                                               const int* __restrict__ boff,
                                               int* __restrict__ rowptr,
                                               int* __restrict__ cursor) {
    __shared__ int sw[8];
    const int tid = threadIdx.x, lane = tid & 63, wv = tid >> 6;
    const int c = blockIdx.x;
    const int i = c * 256 + tid;
    int v = (i < NN) ? deg[i] : 0;
    int incl = v;
    #pragma unroll
    for (int d = 1; d < 64; d <<= 1) {
        int t = __shfl_up(incl, d, 64);
        if (lane >= d) incl += t;
    }
    if (lane == 63) sw[wv] = incl;
    __syncthreads();
    if (wv == 0 && lane < 4) {
        int s4 = sw[lane];
        #pragma unroll
        for (int d = 1; d < 4; d <<= 1) {
            int t = __shfl_up(s4, d, 64);
            if (lane >= d) s4 += t;
        }
        sw[lane + 4] = s4;
    }
    __syncthreads();
    const int excl = boff[c] + ((wv > 0) ? sw[wv - 1 + 4] : 0) + incl - v;
    if (i < NN) { rowptr[i] = excl; cursor[i] = excl; }
    if (c == 0 && tid == 0) rowptr[NN] = EE;
}

__global__ __launch_bounds__(256) void scatter_perm_k(const int* __restrict__ ei,
                                                      int* __restrict__ cursor,
                                                      int* __restrict__ perm,
                                                      int* __restrict__ psrc,
                                                      int* __restrict__ pdst) {
    const int e = blockIdx.x * 256 + threadIdx.x;
    if (e >= EE) return;
    const int d = ei[EE + e];
    const int p = atomicAdd(&cursor[d], 1);
    perm[p] = e;
    psrc[p] = ei[e];
    pdst[p] = d;
}

__global__ __launch_bounds__(256) void softagg1h_k(const int* __restrict__ rowptr,
                                                   const int* __restrict__ psrc,
                                                   const float* __restrict__ a_s,
                                                   const float* __restrict__ a_d,
                                                   const __half* __restrict__ xl,
                                                   const float* __restrict__ bias,
                                                   float* __restrict__ out) {
    const int n = blockIdx.x * 4 + (threadIdx.x >> 6);
    if (n >= NN) return;
    softagg1_node(n, threadIdx.x & 63, rowptr, psrc, a_s, a_d, xl, bias, out);
}

__global__ __launch_bounds__(256) void softagg2h_k(const int* __restrict__ rowptr,
                                                   const int* __restrict__ psrc,
                                                   const float* __restrict__ a_s,
                                                   const float* __restrict__ a_d,
                                                   float* __restrict__ alpha_p,
                                                   float* __restrict__ inv_s,
                                                   const __half* __restrict__ xl,
                                                   const float* __restrict__ bias,
                                                   float* __restrict__ out) {
    const int n = blockIdx.x * 4 + (threadIdx.x >> 6);
    if (n >= NN) return;
    softagg2_node(n, threadIdx.x & 63, rowptr, psrc, a_s, a_d, alpha_p, inv_s, xl, bias, out);
}

__global__ __launch_bounds__(256) void edge_mlp_k(const __half* __restrict__ PQ,
                                                  const float* __restrict__ alpha_p,
                                                  const float* __restrict__ inv_s,
                                                  const int* __restrict__ psrc,
                                                  const int* __restrict__ pdst,
                                                  const int* __restrict__ perm,
                                                  const float* __restrict__ mW1,
                                                  const float* __restrict__ mb1,
                                                  const float* __restrict__ mW2,
                                                  const float* __restrict__ mb2,
                                                  float* __restrict__ out) {
    const int lane = threadIdx.x & 63, wvv = threadIdx.x >> 6;
    const int g = lane >> 4, c = lane & 15;

    const float4 wa0 = *(const float4*)&mW1[32 * 64 + c * 4];
    const float4 wa1 = *(const float4*)&mW1[33 * 64 + c * 4];
    const float4 wa2 = *(const float4*)&mW1[34 * 64 + c * 4];
    const float4 wa3 = *(const float4*)&mW1[35 * 64 + c * 4];
    const float4 b1v = *(const float4*)&mb1[c * 4];
    const float4 w2a = *(const float4*)&mW2[c * 8];
    const float4 w2b = *(const float4*)&mW2[c * 8 + 4];
    const float bo0 = mb2[0], bo1 = mb2[1];

    const h4* PQ4 = (const h4*)PQ;
    const int gw = blockIdx.x * 4 + wvv;
    const int stride4 = gridDim.x * 4 * 4;

    for (int jb = gw * 4; jb < EE; jb += stride4) {
        const int j = jb + g;
        const int s = psrc[j];
        const int d = pdst[j];
        const float4 ar = *(const float4*)&alpha_p[(size_t)j * 4];
        const float4 iv = *(const float4*)&inv_s[(size_t)d * 4];
        const float al0 = ar.x * iv.x, al1 = ar.y * iv.y;
        const float al2 = ar.z * iv.z, al3 = ar.w * iv.w;
        const h4 ph = PQ4[(size_t)s * 32 + c];
        const h4 qh = PQ4[(size_t)d * 32 + 16 + c];
        const float2 pl = __half22float2(ph.a), pm = __half22float2(ph.b);
        const float2 ql = __half22float2(qh.a), qm = __half22float2(qh.b);
        float4 h;
        h.x = pl.x + ql.x + b1v.x; h.y = pl.y + ql.y + b1v.y;
        h.z = pm.x + qm.x + b1v.z; h.w = pm.y + qm.y + b1v.w;
        h.x = fmaf(al0, wa0.x, h.x); h.y = fmaf(al0, wa0.y, h.y);
        h.z = fmaf(al0, wa0.z, h.z); h.w = fmaf(al0, wa0.w, h.w);
        h.x = fmaf(al1, wa1.x, h.x); h.y = fmaf(al1, wa1.y, h.y);
        h.z = fmaf(al1, wa1.z, h.z); h.w = fmaf(al1, wa1.w, h.w);
        h.x = fmaf(al2, wa2.x, h.x); h.y = fmaf(al2, wa2.y, h.y);
        h.z = fmaf(al2, wa2.z, h.z); h.w = fmaf(al2, wa2.w, h.w);
        h.x = fmaf(al3, wa3.x, h.x); h.y = fmaf(al3, wa3.y, h.y);
        h.z = fmaf(al3, wa3.z, h.z); h.w = fmaf(al3, wa3.w, h.w);
        h.x = fmaxf(h.x, 0.f); h.y = fmaxf(h.y, 0.f);
        h.z = fmaxf(h.z, 0.f); h.w = fmaxf(h.w, 0.f);

        float v0 = h.x * w2a.x + h.y * w2a.z + h.z * w2b.x + h.w * w2b.z;
        float v1 = h.x * w2a.y + h.y * w2a.w + h.z * w2b.y + h.w * w2b.w;
        #pragma unroll
        for (int msk = 1; msk < 16; msk <<= 1) {
            v0 += __shfl_xor(v0, msk, 64);
            v1 += __shfl_xor(v1, msk, 64);
        }
        if (c == 0)
            *(float2*)&out[(size_t)perm[j] * 2] = make_float2(v0 + bo0, v1 + bo1);
    }
}

extern "C" void kernel_launch(void* const* d_in, const int* in_sizes, int n_in,
                              void* d_out, int out_size, void* d_ws, size_t ws_size,
                              hipStream_t stream) {
    const float* x        = (const float*)d_in[0];
    const int*   ei       = (const int*)d_in[1];
    // d_in[2] edge_attr: unused (edge_dim=None). d_in[3] flag: unused.
    const float* W1       = (const float*)d_in[4];
    const float* att1_src = (const float*)d_in[5];
    const float* att1_dst = (const float*)d_in[6];
    const float* b1       = (const float*)d_in[7];
    const float* W3       = (const float*)d_in[8];
    const float* att3_src = (const float*)d_in[9];
    const float* att3_dst = (const float*)d_in[10];
    const float* b3       = (const float*)d_in[11];
    const float* mW1      = (const float*)d_in[12];
    const float* mb1      = (const float*)d_in[13];
    const float* mW2      = (const float*)d_in[14];
    const float* mb2      = (const float*)d_in[15];

    float* out_nodes = (float*)d_out;               // [N,32]
    float* out_edges = out_nodes + (size_t)NN * 32; // [E,2]

    // workspace layout (floats/ints)
    float* ws = (float*)d_ws;
    __half*   xlh     = (__half*)ws;                  // N*256 halves (layer-1 GEMM out)
    __half*   xl2h    = (__half*)ws;                  // N*128 halves (layer-2 GEMM out)
    __half*   PQh     = (__half*)ws;                  // N*128 halves, after xl2h dead
    float*    h1      = ws + 12800000;                // N*64
    float*    alpha_p = ws + 16000000;                // E*4 (CSR-order raw w, layer 2)
    float*    a_s     = ws + 25600000;                // N*4
    float*    a_d     = ws + 25800000;                // N*4
    float*    W1pq    = ws + 26000000;                // 32*128
    float*    inv_s   = ws + 26100000;                // N*4
    int*      bsum    = (int*)(ws + 26300000);        // NCH
    int*      boff    = (int*)(ws + 26301000);        // NCH
    int*      deg     = (int*)(ws + 26400000);        // N
    int*      cursor  = (int*)(ws + 26450000);        // N
    int*      rowptr  = (int*)(ws + 26500000);        // N+1
    int*      perm    = (int*)(ws + 26550008);        // E
    int*      psrc    = (int*)(ws + 27350008);        // E
    int*      pdst    = (int*)(ws + 28150008);        // E

    const int NB4 = (NN + 3) / 4;

    // 1) zero deg
    hipMemsetAsync(deg, 0, (size_t)NN * 4, stream);
    // 2) fused: count_deg + pack_w1 + layer-1 GEMM (64x128 tiles, 1564 GEMM blocks)
    csr_gemm1_k<<<EB + 16 + GR64 * 2, 256, 0, stream>>>(ei, deg, mW1, W1pq,
                                                        x, W1, xlh,
                                                        att1_src, att1_dst, a_s, a_d);
    // 3) multi-block exclusive scan -> rowptr/cursor
    scan1_k<<<NCH, 256, 0, stream>>>(deg, bsum);
    scan2_k<<<1, 256, 0, stream>>>(bsum, boff);
    scan3_k<<<NCH, 256, 0, stream>>>(deg, boff, rowptr, cursor);
    // 4) scatter edges into CSR order
    scatter_perm_k<<<EB, 256, 0, stream>>>(ei, cursor, perm, psrc, pdst);
    // 5) layer-1 softmax+aggregate
    softagg1h_k<<<NB4, 256, 0, stream>>>(rowptr, psrc, a_s, a_d, xlh, b1, h1);
    // 6) layer-2 GEMM (64x128 tile; M=128 -> one col tile, 782 blocks)
    gemm_att48_k<32, true><<<dim3(GR64, 1), 256, 0, stream>>>(h1, W3, xl2h,
                                                              att3_src, att3_dst,
                                                              a_s, a_d, NN, 64, NH * 32);
    // 7) layer-2 softmax+aggregate
    softagg2h_k<<<NB4, 256, 0, stream>>>(rowptr, psrc, a_s, a_d, alpha_p, inv_s, xl2h, b3,
                                         out_nodes);
    // 8) PQ GEMM (xl2h dead -> PQh aliases it)
    gemm_pq48_k<<<dim3(GR64, 1), 256, 0, stream>>>(out_nodes, W1pq, PQh, NN, 32, 128);
    // 9) edge MLP
    edge_mlp_k<<<2048, 256, 0, stream>>>(PQh, alpha_p, inv_s, psrc, pdst, perm,
                                         mW1, mb1, mW2, mb2, out_edges);
}